// Round 10
// baseline (582.263 us; speedup 1.0000x reference)
//
#include <hip/hip_runtime.h>
#include <hip/hip_bf16.h>

// R16: occupancy push on R15 (412us bench / 327us dispatch, absmax 0.0068).
// Measured: latency/barrier-bound (VALU cut neutral, balance cut -6%,
// MfmaUtil 21%), Occupancy stuck at 45% = 2 blocks/CU (LDS 71KB).
// Change: NB 4->2 (40 real tokens, M padded to 48 = 3 m-tiles).
//   LDS 71.1KB -> 46.4KB -> 3 blocks/CU, 24 waves (75%); per-phase critical
//   path 3->2 m-iters; gemmT K 3->2 steps (K-pad 96->64).
// Pad-row correctness: x pad rows zeroed at staging (all downstream pad rows
// stay finite = relu(bias)); gemmT/mwT weights are ZERO for pad tokens so
// pad garbage never crosses tokens; grc/wrc get a zeroed 3rd row for the
// tok/20==2 init reads; maskv zero-extended (pad scores = 0); out store
// guarded tok<MTOK. Everything else identical to R15.

typedef short sx8 __attribute__((ext_vector_type(8)));
typedef short sx4 __attribute__((ext_vector_type(4)));
typedef float fx4 __attribute__((ext_vector_type(4)));
typedef unsigned ux2 __attribute__((ext_vector_type(2)));

#define TB   512
#define NW   8
#define NB   2      // batch elems per block
#define MTOK 40     // NB*20 real tokens
#define MPAD 48     // padded tokens (3 m-tiles)
#define MT   3      // m-tiles of 16
#define CHH  384    // halves per k-chunk: MPAD x 8
#define CHG  128    // halves per bufG chunk: 16 tok x 8
#define KPW  64     // wT K-pad (>=48, mult of 32)

// LDS byte offsets (16B aligned)
#define OFF_BUFT 0        // 20 chunks x 768B = 15360
#define OFF_BUFA 15360    // 16 chunks = 12288
#define OFF_BUFH 27648    // 8 chunks  = 6144
#define OFF_BUFG 33792    // 16 chunks x 256B = 4096
#define OFF_BIAS 37888    // 848 f32 = 3392
#define OFF_GRC  41280    // 3x112 f32 = 1344 (row 2 = zeros for pad toks)
#define OFF_WRC  42624    // 3x112 f32 = 1344
#define OFF_SC   43968    // 48 f32
#define OFF_MASK 44160    // 48 f32 (rows 40-47 zeroed)
#define OFF_MSUM 44352    // 4 f32 (pad 16)
#define OFF_WTM  44368    // 16x64 bf16 = 2048 (mwT, then seT)
#define SMEM_BYTES 46416  // -> 3 blocks/CU

#define B_M1B0 0
#define B_M1B1 152
#define B_M2B0 256
#define B_M2B1 360
#define B_ATB0 416
#define B_ATB1 520
#define B_HPB0 624
#define B_HPB1 728
#define B_HPB2 832

// d_ws offsets in halves; each layer as wA[k8][nl][8]
#define WS_M1W0  0        // KP=32,  NR=160
#define WS_M1W1  5120     // KP=160, NR=112
#define WS_M2W0  23040    // KP=128, NR=112
#define WS_M2W1  37376    // KP=128, NR=64
#define WS_ATW0  45568    // KP=128, NR=112 (rows 0..99)
#define WS_ATW1  59904    // KP=128, NR=112
#define WS_HPW0  74240    // KP=64,  NR=112 (rows 0..49)
#define WS_HPW1  81408    // KP=128, NR=112
#define WS_HPW2  95744    // KP=128, NR=16
#define WS_ATW0H 97792    // KP=128, NR=112 (atw0 rows 100..199)
#define WS_HPW0H 112128   // KP=64,  NR=112 (hpw0 rows 50..99)
#define WS_ATW2  119296   // KP=128, NR=16  (atw2 as 100x1, row 0)

__device__ __forceinline__ short f2b(float f) {
    unsigned u = __builtin_bit_cast(unsigned, f);
    u += 0x7FFFu + ((u >> 16) & 1u);          // RNE
    return (short)(u >> 16);
}
__device__ __forceinline__ float b2f(short h) {
    unsigned u = ((unsigned)(unsigned short)h) << 16;
    return __builtin_bit_cast(float, u);
}
// 4x f32 -> 4x bf16 via compiler packed cvt (v_cvt_pk_bf16_f32, RNE).
__device__ __forceinline__ sx4 pack4(fx4 v) {
    __hip_bfloat162 lo = __float22bfloat162_rn(make_float2(v[0], v[1]));
    __hip_bfloat162 hi = __float22bfloat162_rn(make_float2(v[2], v[3]));
    ux2 p;
    unsigned ulo, uhi;
    __builtin_memcpy(&ulo, &lo, 4);
    __builtin_memcpy(&uhi, &hi, 4);
    p[0] = ulo; p[1] = uhi;
    return __builtin_bit_cast(sx4, p);
}

// ---- prologue: W[K][N] f32 -> wA[k8][nl][8] bf16 in d_ws (zero padded)
__device__ __forceinline__ void stg(const float* __restrict__ W, int N,
                                    int KR, int KPAD, int NR, int Nsrc,
                                    short* dst, int gtid, int gsz) {
    int K8 = KPAD >> 3;
    for (int idx = gtid; idx < NR * K8; idx += gsz) {
        int k8 = idx / NR, nl = idx - k8 * NR;
        int k0 = k8 << 3;
        sx8 h;
        #pragma unroll
        for (int i = 0; i < 8; ++i) {
            int k = k0 + i;
            float v = (k < KR && nl < Nsrc) ? W[k * N + nl] : 0.f;
            h[i] = f2b(v);
        }
        *(sx8*)(dst + (k8 * NR + nl) * 8) = h;
    }
}

__global__ void stage_weights(
    const float* __restrict__ m1w0, const float* __restrict__ m1w1,
    const float* __restrict__ m2w0, const float* __restrict__ m2w1,
    const float* __restrict__ atw0, const float* __restrict__ atw1,
    const float* __restrict__ hpw0, const float* __restrict__ hpw1,
    const float* __restrict__ hpw2, const float* __restrict__ atw2,
    short* __restrict__ ws)
{
    int gtid = blockIdx.x * blockDim.x + threadIdx.x;
    int gsz = gridDim.x * blockDim.x;
    stg(m1w0, 150, 13, 32, 160, 150, ws + WS_M1W0, gtid, gsz);
    stg(m1w1, 100, 150, 160, 112, 100, ws + WS_M1W1, gtid, gsz);
    stg(m2w0, 100, 100, 128, 112, 100, ws + WS_M2W0, gtid, gsz);
    stg(m2w1, 50, 100, 128, 64, 50, ws + WS_M2W1, gtid, gsz);
    stg(atw0, 100, 100, 128, 112, 100, ws + WS_ATW0, gtid, gsz);
    stg(atw1, 100, 100, 128, 112, 100, ws + WS_ATW1, gtid, gsz);
    stg(hpw0, 100, 50, 64, 112, 100, ws + WS_HPW0, gtid, gsz);
    stg(hpw1, 100, 100, 128, 112, 100, ws + WS_HPW1, gtid, gsz);
    stg(hpw2, 7, 100, 128, 16, 7, ws + WS_HPW2, gtid, gsz);
    stg(atw0 + 100 * 100, 100, 100, 128, 112, 100, ws + WS_ATW0H, gtid, gsz);
    stg(hpw0 + 50 * 100, 100, 50, 64, 112, 100, ws + WS_HPW0H, gtid, gsz);
    stg(atw2, 1, 100, 128, 16, 1, ws + WS_ATW2, gtid, gsz);
}

// ---- main GEMM, NG*2-unit decomposition: unit = (nt-pair, m-half) with
// m-halves {tiles 0-1, tile 2} (MT=3). NT=7 -> 8 units, 1/wave.
// Pad output columns are exactly 0 via zero-padded weights/bias/init.
template <int KT, int NT, bool RELU, bool UINIT>
__device__ __forceinline__ void gemm(const short* __restrict__ wg, int NR,
                                     const short* bIn, short* bOut,
                                     const float* initp, int initBstride,
                                     int wave, int lm, int lq) {
    constexpr int NG = (NT + 1) / 2;
    constexpr int NU = NG * 2;
    for (int u = wave; u < NU; u += NW) {
        int ng = u >> 1, mh = u & 1;
        int nt0 = ng * 2, nt1 = nt0 + 1;
        bool hasN1 = !((NT & 1) && (ng == NG - 1));
        sx8 a0[KT], a1[KT];
        #pragma unroll
        for (int kt = 0; kt < KT; ++kt)
            a0[kt] = *(const sx8*)(wg + ((kt * 4 + lq) * NR + nt0 * 16 + lm) * 8);
        if (hasN1) {
            #pragma unroll
            for (int kt = 0; kt < KT; ++kt)
                a1[kt] = *(const sx8*)(wg + ((kt * 4 + lq) * NR + nt1 * 16 + lm) * 8);
        }
        int n0l0 = nt0 * 16 + lq * 4;
        int n0l1 = nt1 * 16 + lq * 4;
        fx4 ib0, ib1;
        if (UINIT) {
            ib0 = *(const fx4*)(initp + n0l0);
            if (hasN1) ib1 = *(const fx4*)(initp + n0l1);
        }
        int mstart = mh ? 2 : 0;          // MT=3 split {2,1}
        int mcount = mh ? 1 : 2;
        #pragma unroll 2
        for (int mi = 0; mi < mcount; ++mi) {
            int mt = mstart + mi;
            int tok = mt * 16 + lm;
            sx8 bfr[KT];
            #pragma unroll
            for (int kt = 0; kt < KT; ++kt)
                bfr[kt] = *(const sx8*)(bIn + (kt * 4 + lq) * CHH + tok * 8);
            fx4 acc0, acc1;
            if (UINIT) acc0 = ib0;
            else acc0 = *(const fx4*)(initp + (tok / 20) * initBstride + n0l0);
            if (hasN1) {
                if (UINIT) acc1 = ib1;
                else acc1 = *(const fx4*)(initp + (tok / 20) * initBstride + n0l1);
            }
            #pragma unroll
            for (int kt = 0; kt < KT; ++kt) {
                acc0 = __builtin_amdgcn_mfma_f32_16x16x32_bf16(a0[kt], bfr[kt], acc0, 0, 0, 0);
                if (hasN1)
                    acc1 = __builtin_amdgcn_mfma_f32_16x16x32_bf16(a1[kt], bfr[kt], acc1, 0, 0, 0);
            }
            if (RELU) {
                #pragma unroll
                for (int r = 0; r < 4; ++r) acc0[r] = fmaxf(acc0[r], 0.f);
            }
            *(sx4*)(bOut + (nt0 * 2 + (lq >> 1)) * CHH + tok * 8 + (lq & 1) * 4) = pack4(acc0);
            if (hasN1) {
                if (RELU) {
                    #pragma unroll
                    for (int r = 0; r < 4; ++r) acc1[r] = fmaxf(acc1[r], 0.f);
                }
                *(sx4*)(bOut + (nt1 * 2 + (lq >> 1)) * CHH + tok * 8 + (lq & 1) * 4) = pack4(acc1);
            }
        }
    }
}

// ---- reduction GEMM (gcon/hcon): M=16 single tile from bufG, f32 out.
// outF[b*112+n] for b<NB; rows >=NB discarded (garbage stays in its lane).
template <int KT, int NT>
__device__ __forceinline__ void gemmR(const short* __restrict__ wg, int NR,
                                      const short* bG, float* outF,
                                      const float* biasp,
                                      int wave, int lm, int lq) {
    constexpr int NG = (NT + 1) / 2;
    for (int u = wave; u < NG; u += NW) {
        int nt0 = u * 2, nt1 = nt0 + 1;
        bool hasN1 = !((NT & 1) && (u == NG - 1));
        sx8 a0[KT], a1[KT], bfr[KT];
        #pragma unroll
        for (int kt = 0; kt < KT; ++kt) {
            a0[kt] = *(const sx8*)(wg + ((kt * 4 + lq) * NR + nt0 * 16 + lm) * 8);
            bfr[kt] = *(const sx8*)(bG + (kt * 4 + lq) * CHG + lm * 8);
        }
        if (hasN1) {
            #pragma unroll
            for (int kt = 0; kt < KT; ++kt)
                a1[kt] = *(const sx8*)(wg + ((kt * 4 + lq) * NR + nt1 * 16 + lm) * 8);
        }
        int n0l0 = nt0 * 16 + lq * 4;
        int n0l1 = nt1 * 16 + lq * 4;
        fx4 acc0 = *(const fx4*)(biasp + n0l0);
        fx4 acc1;
        if (hasN1) acc1 = *(const fx4*)(biasp + n0l1);
        #pragma unroll
        for (int kt = 0; kt < KT; ++kt) {
            acc0 = __builtin_amdgcn_mfma_f32_16x16x32_bf16(a0[kt], bfr[kt], acc0, 0, 0, 0);
            if (hasN1)
                acc1 = __builtin_amdgcn_mfma_f32_16x16x32_bf16(a1[kt], bfr[kt], acc1, 0, 0, 0);
        }
        if (lm < NB) {
            *(fx4*)(outF + lm * 112 + n0l0) = acc0;
            if (hasN1) *(fx4*)(outF + lm * 112 + n0l1) = acc1;
        }
    }
}

// ---- transposed-A reduction GEMM (glob/wsum): out[b][j] = sum_tok
//      wT[b][tok]*act[tok][j], K = tokens (40 real, KP=64), D -> bufG bf16.
// K order permuted within 8-groups by +lq*2 (mirrored in wT build).
// wT rows >= MTOK are zero, so pad-token act garbage contributes 0
// (act pad rows are kept FINITE by zeroed x staging).
template <int NT>
__device__ __forceinline__ void gemmT(const short* __restrict__ act,
                                      const short* __restrict__ wT,
                                      short* __restrict__ bG,
                                      int wave, int lm, int lq) {
    for (int nt = wave; nt < NT; nt += NW) {
        int j = nt * 16 + lm;
        const short* ap = act + (j >> 3) * CHH + (j & 7);
        fx4 acc = {0.f, 0.f, 0.f, 0.f};
        #pragma unroll
        for (int kt = 0; kt < 2; ++kt) {
            int tok0 = kt * 32 + lq * 8;
            int tok0e = (tok0 < MPAD) ? tok0 : 0; // rows >= MPAD zero in wT
            sx8 a;
            #pragma unroll
            for (int i = 0; i < 8; ++i) {
                int ii = (i + lq * 2) & 7;         // bank-staggered K permute
                a[i] = ap[(tok0e + ii) * 8];
            }
            sx8 b = *(const sx8*)(wT + lm * KPW + tok0);
            acc = __builtin_amdgcn_mfma_f32_16x16x32_bf16(a, b, acc, 0, 0, 0);
        }
        if (lm < NB) {   // D[row=j][col=b]; only b<NB real
            *(sx4*)(bG + (nt * 2 + (lq >> 1)) * CHG + lm * 8 + (lq & 1) * 4) = pack4(acc);
        }
    }
}

// zero chunks 14,15 of a 16-chunk activation buffer (2 chunks x 48 rows)
__device__ __forceinline__ void zpad(short* buf, int tid) {
    for (int i = tid; i < 96; i += TB) {
        sx8 z = {0, 0, 0, 0, 0, 0, 0, 0};
        *(sx8*)(buf + 14 * CHH + i * 8) = z;
    }
}

__global__ __launch_bounds__(TB, 6) void sp_mfma_bf16(
    const float* __restrict__ state,
    const float* __restrict__ m1b0, const float* __restrict__ m1b1,
    const float* __restrict__ m2b0, const float* __restrict__ m2b1,
    const float* __restrict__ atb0, const float* __restrict__ atb1,
    const float* __restrict__ atb2,
    const float* __restrict__ hpb0, const float* __restrict__ hpb1,
    const float* __restrict__ hpb2,
    const short* __restrict__ ws,
    float* __restrict__ out)
{
    __shared__ __align__(16) unsigned char smem[SMEM_BYTES];
    short* bufT  = (short*)(smem + OFF_BUFT);
    short* bufA  = (short*)(smem + OFF_BUFA);
    short* bufH2 = (short*)(smem + OFF_BUFH);
    short* bufG  = (short*)(smem + OFF_BUFG);
    float* biasv = (float*)(smem + OFF_BIAS);
    float* grc   = (float*)(smem + OFF_GRC);
    float* wrc   = (float*)(smem + OFF_WRC);
    float* scv   = (float*)(smem + OFF_SC);
    float* maskv = (float*)(smem + OFF_MASK);
    float* msum  = (float*)(smem + OFF_MSUM);
    short* wTm   = (short*)(smem + OFF_WTM);

    const int tid  = threadIdx.x;
    const int lane = tid & 63;
    const int wave = tid >> 6;
    const int lm   = lane & 15;
    const int lq   = lane >> 4;
    const long gt0 = (long)blockIdx.x * MTOK;

    // ---- P1: biases, mask (zero-extended), x -> bufA chunks 0..3 (pad rows
    //          zeroed), bufG zero-init, grc/wrc pad-row (row 2) zero
    {
        const float* bs[9] = {m1b0, m1b1, m2b0, m2b1, atb0, atb1, hpb0, hpb1, hpb2};
        const int off[9] = {B_M1B0, B_M1B1, B_M2B0, B_M2B1, B_ATB0, B_ATB1, B_HPB0, B_HPB1, B_HPB2};
        const int sz[9]  = {150, 100, 100, 50, 100, 100, 100, 100, 7};
        const int pd[9]  = {152, 104, 104, 56, 104, 104, 104, 104, 16};
        #pragma unroll
        for (int r = 0; r < 9; ++r)
            for (int i = tid; i < pd[r]; i += TB)
                biasv[off[r] + i] = (i < sz[r]) ? bs[r][i] : 0.f;
        for (int t = tid; t < MPAD; t += TB)
            maskv[t] = (t < MTOK) ? state[(gt0 + t) * 14 + 13] : 0.f;
        for (int t = tid; t < 112; t += TB) {
            grc[2 * 112 + t] = 0.f;
            wrc[2 * 112 + t] = 0.f;
        }
        for (int t = tid; t < 256; t += TB) {
            sx8 z = {0, 0, 0, 0, 0, 0, 0, 0};
            *(sx8*)(bufG + t * 8) = z;
        }
        for (int idx = tid; idx < MPAD * 4; idx += TB) {
            int row = idx >> 2, seg = idx & 3;
            sx8 h = {0, 0, 0, 0, 0, 0, 0, 0};
            if (row < MTOK) {
                const float* xp = state + (gt0 + row) * 14;
                #pragma unroll
                for (int i = 0; i < 8; ++i) {
                    int k = seg * 8 + i;
                    float v = (k < 13) ? xp[k] : 0.f;
                    h[i] = f2b(v);
                }
            }
            *(sx8*)(bufA + seg * CHH + row * 8) = h;
        }
    }
    __syncthreads();

    // ---- P2: msum + m1L0 (13->150, relu): x(bufA) -> bufT
    if (tid < NB) {
        float s = 0.f;
        #pragma unroll
        for (int n = 0; n < 20; ++n) s += maskv[tid * 20 + n];
        msum[tid] = s;
    }
    gemm<1, 10, true, true>(ws + WS_M1W0, 160, bufA, bufT, biasv + B_M1B0, 0,
                            wave, lm, lq);
    __syncthreads();

    // ---- P3: m1L1 (150->100, relu): bufT -> bufA (h1) + mwT build
    gemm<5, 7, true, true>(ws + WS_M1W1, 112, bufT, bufA, biasv + B_M1B1, 0,
                           wave, lm, lq);
    zpad(bufA, tid);
    for (int t = tid; t < 16 * KPW; t += TB) {   // mwT[b][tperm], 16xKPW
        int b = t / KPW, tp = t - b * KPW;
        int tau = (tp & ~7) | ((tp + ((tp >> 3) & 3) * 2) & 7);
        float v = 0.f;
        if (b < NB && tau < MTOK && tau / 20 == b) {
            float ms = msum[b];
            v = (ms > 0.f) ? maskv[tau] / ms : 0.f;
        }
        wTm[t] = f2b(v);
    }
    __syncthreads();

    // ---- P4: glob (gemmT: h1 x mwT -> bufG) + m2L0 (100->100, relu)
    gemmT<7>(bufA, wTm, bufG, wave, lm, lq);
    gemm<4, 7, true, true>(ws + WS_M2W0, 112, bufA, bufT, biasv + B_M2B0, 0,
                           wave, lm, lq);
    zpad(bufT, tid);
    __syncthreads();

    // ---- P5: gcon (gemmR, waves 0-3) + m2L1 (100->50, waves 4-7)
    gemmR<4, 7>(ws + WS_ATW0H, 112, bufG, grc, biasv + B_ATB0, wave, lm, lq);
    gemm<4, 4, false, true>(ws + WS_M2W1, 64, bufT, bufH2, biasv + B_M2B1, 0,
                            (wave + 4) & 7, lm, lq);
    __syncthreads();

    // ---- P6: atL0 (100->100, relu, init=gcon): h1(bufA) -> bufT
    gemm<4, 7, true, false>(ws + WS_ATW0, 112, bufA, bufT, grc, 112,
                            wave, lm, lq);
    __syncthreads();

    // ---- P7: atL1 (100->100, relu): bufT -> bufA (ta2)
    gemm<4, 7, true, true>(ws + WS_ATW1, 112, bufT, bufA, biasv + B_ATB1, 0,
                           wave, lm, lq);
    __syncthreads();

    // ---- P8: scores via MFMA (ta2 @ atw2), exp/mask epilogue -> scv
    //          (pad tokens: maskv=0 -> scv=0)
    {
        float atb2s = atb2[0];
        sx8 afr[4];
        #pragma unroll
        for (int kt = 0; kt < 4; ++kt)
            afr[kt] = *(const sx8*)(ws + WS_ATW2 + ((kt * 4 + lq) * 16 + lm) * 8);
        for (int mt = wave; mt < MT; mt += NW) {
            int tok = mt * 16 + lm;
            fx4 acc = {0.f, 0.f, 0.f, 0.f};
            const short* bp = bufA + tok * 8;
            #pragma unroll
            for (int kt = 0; kt < 4; ++kt) {
                sx8 b = *(const sx8*)(bp + (kt * 4 + lq) * CHH);
                acc = __builtin_amdgcn_mfma_f32_16x16x32_bf16(afr[kt], b, acc, 0, 0, 0);
            }
            if (lq == 0) {
                float s = (acc[0] + atb2s) * maskv[tok];
                scv[tok] = (s != 0.f) ? __expf(s) : 0.f;
            }
        }
    }
    __syncthreads();

    // ---- P9: seT build (ssum inline): seT[b][tperm] = se/ssum
    for (int t = tid; t < 16 * KPW; t += TB) {
        int b = t / KPW, tp = t - b * KPW;
        int tau = (tp & ~7) | ((tp + ((tp >> 3) & 3) * 2) & 7);
        float v = 0.f;
        if (b < NB && tau < MTOK && tau / 20 == b) {
            float ss = 0.f;
            #pragma unroll
            for (int n = 0; n < 20; ++n) ss += scv[b * 20 + n];
            v = (ss > 0.f) ? scv[tau] / ss : 0.f;
        }
        wTm[t] = f2b(v);
    }
    __syncthreads();

    // ---- P10: wsum (gemmT: h2 x seT -> bufG chunks 0..7)
    gemmT<4>(bufH2, wTm, bufG, wave, lm, lq);
    __syncthreads();

    // ---- P11: hcon (gemmR: wrc = hpb0 + wsum @ hpw0[50:100])
    gemmR<2, 7>(ws + WS_HPW0H, 112, bufG, wrc, biasv + B_HPB0, wave, lm, lq);
    __syncthreads();

    // ---- P12: hpL0 (50->100, relu, init=hcon): h2(bufH2) -> bufT
    gemm<2, 7, true, false>(ws + WS_HPW0, 112, bufH2, bufT, wrc, 112,
                            wave, lm, lq);
    __syncthreads();

    // ---- P13: hpL1 (100->100, relu): bufT -> bufA
    gemm<4, 7, true, true>(ws + WS_HPW1, 112, bufT, bufA, biasv + B_HPB1, 0,
                           wave, lm, lq);
    __syncthreads();

    // ---- P14: hpL2 (100->7) -> global out; A-frags hoisted; tok guard
    {
        sx8 afr[4];
        #pragma unroll
        for (int kt = 0; kt < 4; ++kt)
            afr[kt] = *(const sx8*)(ws + WS_HPW2 + ((kt * 4 + lq) * 16 + lm) * 8);
        fx4 ib = *(const fx4*)(biasv + B_HPB2 + lq * 4);
        for (int mt = wave; mt < MT; mt += NW) {
            int tok = mt * 16 + lm;
            fx4 acc = ib;
            const short* bp = bufA + tok * 8;
            #pragma unroll
            for (int kt = 0; kt < 4; ++kt) {
                sx8 b = *(const sx8*)(bp + (kt * 4 + lq) * CHH);
                acc = __builtin_amdgcn_mfma_f32_16x16x32_bf16(afr[kt], b, acc, 0, 0, 0);
            }
            if (tok < MTOK) {
                #pragma unroll
                for (int r = 0; r < 4; ++r) {
                    int n = lq * 4 + r;
                    if (n < 7) out[(gt0 + tok) * 7 + n] = acc[r];
                }
            }
        }
    }
}

extern "C" void kernel_launch(void* const* d_in, const int* in_sizes, int n_in,
                              void* d_out, int out_size, void* d_ws, size_t ws_size,
                              hipStream_t stream) {
    int si = 20, wb = 0;
    if (in_sizes[0] > 1000000) { si = 0; wb = 1; }
    const float* state = (const float*)d_in[si];
    const float* W[20];
    for (int i = 0; i < 20; ++i) W[i] = (const float*)d_in[wb + i];
    float* out = (float*)d_out;
    short* ws = (short*)d_ws;
    int Btot = in_sizes[si] / (20 * 14);
    int nblocks = Btot / NB;   // 2 b's (40 tokens) per block -> 16384

    hipLaunchKernelGGL(stage_weights, dim3(128), dim3(256), 0, stream,
        W[0], W[2], W[4], W[6], W[8], W[10], W[14], W[16], W[18], W[12], ws);

    hipLaunchKernelGGL(sp_mfma_bf16, dim3(nblocks), dim3(TB), 0, stream,
        state,
        W[1], W[3],           // m1b0, m1b1
        W[5], W[7],           // m2b0, m2b1
        W[9], W[11],          // atb0, atb1
        W[13],                // atb2
        W[15], W[17], W[19],  // hpb0, hpb1, hpb2
        ws, out);
}

// Round 12
// 484.878 us; speedup vs baseline: 1.2008x; 1.2008x over previous
//
#include <hip/hip_runtime.h>
#include <hip/hip_bf16.h>

// R17 (resubmit; prior round was an infra failure — kernel never ran).
// Per-wave pipeline rewrite. R16 post-mortem: occupancy was NOT binding
// (67% occ -> 57% SLOWER; WRITE_SIZE 278MB = launch_bounds-induced spill;
// per-block fixed overhead ~40%). Real bottleneck: 13 serial block-wide
// phases, each ~3.4k cyc vs ~1k true dep chain (barrier convergence+drain).
// New structure: one WAVE = one batch elem (20 tokens), full pipeline in its
// OWN LDS region (R1=20ch, R2=16ch, R3=8ch of 20-row chunks; m-tiles = rows
// [0..15] and overlapping [4..19], duplicate rows recompute identical bytes).
// Cross-token glue (msum/glob/scores/wsum) = per-wave VALU (f32, more
// precise than R15's bf16 gemmT). Only gcon/hcon stay block-level (shared
// bufG + verified gemmR): 5 barriers total vs 13. TB=256, NB=4/block,
// LDS 66.2KB -> 2 blocks/CU. Pad-col safety: same zero-weight arguments as
// R12 (garbage is finite x zeroed ws rows = 0; audited per consumer).
// Fallback if this regresses: R15 (412us bench / 327us dispatch).

typedef short sx8 __attribute__((ext_vector_type(8)));
typedef short sx4 __attribute__((ext_vector_type(4)));
typedef float fx4 __attribute__((ext_vector_type(4)));
typedef unsigned ux2 __attribute__((ext_vector_type(2)));

#define TB   256
#define NW   4
#define NB   4      // batch elems per block = waves per block
#define CHW  160    // halves per act chunk: 20 rows x 8
#define CHG  128    // halves per bufG chunk: 16 rows x 8
#define WREG 7040   // halves per wave region block (44 chunks)

// LDS byte offsets (16B aligned)
#define OFF_ACT  0        // 4 waves x 14080 B = 56320
#define OFF_BUFG 56320    // 16 chunks x 256B = 4096
#define OFF_BIAS 60416    // 848 f32 = 3392
#define OFF_RC   63808    // 4x112 f32 = 1792 (grc, then wrc)
#define OFF_SC   65600    // 80 f32 = 320
#define OFF_MASK 65920    // 80 f32 = 320
#define SMEM_BYTES 66240  // -> 2 blocks/CU

#define B_M1B0 0
#define B_M1B1 152
#define B_M2B0 256
#define B_M2B1 360
#define B_ATB0 416
#define B_ATB1 520
#define B_HPB0 624
#define B_HPB1 728
#define B_HPB2 832

// d_ws offsets in halves; each layer as wA[k8][nl][8]
#define WS_M1W0  0        // KP=32,  NR=160
#define WS_M1W1  5120     // KP=160, NR=112
#define WS_M2W0  23040    // KP=128, NR=112
#define WS_M2W1  37376    // KP=128, NR=64
#define WS_ATW0  45568    // KP=128, NR=112 (rows 0..99)
#define WS_ATW1  59904    // KP=128, NR=112
#define WS_HPW0  74240    // KP=64,  NR=112 (rows 0..49)
#define WS_HPW1  81408    // KP=128, NR=112
#define WS_HPW2  95744    // KP=128, NR=16
#define WS_ATW0H 97792    // KP=128, NR=112 (atw0 rows 100..199)
#define WS_HPW0H 112128   // KP=64,  NR=112 (hpw0 rows 50..99)
#define WS_ATW2  119296   // KP=128, NR=16  (atw2 as 100x1, row 0)

__device__ __forceinline__ short f2b(float f) {
    unsigned u = __builtin_bit_cast(unsigned, f);
    u += 0x7FFFu + ((u >> 16) & 1u);          // RNE
    return (short)(u >> 16);
}
__device__ __forceinline__ float b2f(short h) {
    unsigned u = ((unsigned)(unsigned short)h) << 16;
    return __builtin_bit_cast(float, u);
}
// 4x f32 -> 4x bf16 via compiler packed cvt (v_cvt_pk_bf16_f32, RNE).
__device__ __forceinline__ sx4 pack4(fx4 v) {
    __hip_bfloat162 lo = __float22bfloat162_rn(make_float2(v[0], v[1]));
    __hip_bfloat162 hi = __float22bfloat162_rn(make_float2(v[2], v[3]));
    ux2 p;
    unsigned ulo, uhi;
    __builtin_memcpy(&ulo, &lo, 4);
    __builtin_memcpy(&uhi, &hi, 4);
    p[0] = ulo; p[1] = uhi;
    return __builtin_bit_cast(sx4, p);
}

// ---- prologue: W[K][N] f32 -> wA[k8][nl][8] bf16 in d_ws (zero padded)
__device__ __forceinline__ void stg(const float* __restrict__ W, int N,
                                    int KR, int KPAD, int NR, int Nsrc,
                                    short* dst, int gtid, int gsz) {
    int K8 = KPAD >> 3;
    for (int idx = gtid; idx < NR * K8; idx += gsz) {
        int k8 = idx / NR, nl = idx - k8 * NR;
        int k0 = k8 << 3;
        sx8 h;
        #pragma unroll
        for (int i = 0; i < 8; ++i) {
            int k = k0 + i;
            float v = (k < KR && nl < Nsrc) ? W[k * N + nl] : 0.f;
            h[i] = f2b(v);
        }
        *(sx8*)(dst + (k8 * NR + nl) * 8) = h;
    }
}

__global__ void stage_weights(
    const float* __restrict__ m1w0, const float* __restrict__ m1w1,
    const float* __restrict__ m2w0, const float* __restrict__ m2w1,
    const float* __restrict__ atw0, const float* __restrict__ atw1,
    const float* __restrict__ hpw0, const float* __restrict__ hpw1,
    const float* __restrict__ hpw2, const float* __restrict__ atw2,
    short* __restrict__ ws)
{
    int gtid = blockIdx.x * blockDim.x + threadIdx.x;
    int gsz = gridDim.x * blockDim.x;
    stg(m1w0, 150, 13, 32, 160, 150, ws + WS_M1W0, gtid, gsz);
    stg(m1w1, 100, 150, 160, 112, 100, ws + WS_M1W1, gtid, gsz);
    stg(m2w0, 100, 100, 128, 112, 100, ws + WS_M2W0, gtid, gsz);
    stg(m2w1, 50, 100, 128, 64, 50, ws + WS_M2W1, gtid, gsz);
    stg(atw0, 100, 100, 128, 112, 100, ws + WS_ATW0, gtid, gsz);
    stg(atw1, 100, 100, 128, 112, 100, ws + WS_ATW1, gtid, gsz);
    stg(hpw0, 100, 50, 64, 112, 100, ws + WS_HPW0, gtid, gsz);
    stg(hpw1, 100, 100, 128, 112, 100, ws + WS_HPW1, gtid, gsz);
    stg(hpw2, 7, 100, 128, 16, 7, ws + WS_HPW2, gtid, gsz);
    stg(atw0 + 100 * 100, 100, 100, 128, 112, 100, ws + WS_ATW0H, gtid, gsz);
    stg(hpw0 + 50 * 100, 100, 50, 64, 112, 100, ws + WS_HPW0H, gtid, gsz);
    stg(atw2, 1, 100, 128, 16, 1, ws + WS_ATW2, gtid, gsz);
}

// ---- per-wave GEMM: one batch elem (20 tokens) entirely within this wave.
// m-tiles: rows [0..15] and overlapping [4..19] (dup rows 4..15 recompute
// identical values -> benign rewrites). A = weights frag from ws; B = own
// LDS region; D packed bf16 to own LDS region. init from initp (bias row or
// grc/wrc row) -- pad-col init garbage is finite and killed by zeroed ws
// rows downstream (R12-verified argument).
template <int KT, int NT, bool RELU>
__device__ __forceinline__ void wgemm(const short* __restrict__ wg, int NR,
                                      const short* bIn, short* bOut,
                                      const float* initp, int lm, int lq) {
    #pragma unroll 2
    for (int nt = 0; nt < NT; ++nt) {
        sx8 a[KT];
        #pragma unroll
        for (int kt = 0; kt < KT; ++kt)
            a[kt] = *(const sx8*)(wg + ((kt * 4 + lq) * NR + nt * 16 + lm) * 8);
        int n0 = nt * 16 + lq * 4;
        fx4 ib = *(const fx4*)(initp + n0);
        #pragma unroll
        for (int mt = 0; mt < 2; ++mt) {
            int tok = (mt ? 4 : 0) + lm;
            sx8 bfr[KT];
            #pragma unroll
            for (int kt = 0; kt < KT; ++kt)
                bfr[kt] = *(const sx8*)(bIn + (kt * 4 + lq) * CHW + tok * 8);
            fx4 acc = ib;
            #pragma unroll
            for (int kt = 0; kt < KT; ++kt)
                acc = __builtin_amdgcn_mfma_f32_16x16x32_bf16(a[kt], bfr[kt], acc, 0, 0, 0);
            if (RELU) {
                #pragma unroll
                for (int r = 0; r < 4; ++r) acc[r] = fmaxf(acc[r], 0.f);
            }
            *(sx4*)(bOut + (nt * 2 + (lq >> 1)) * CHW + tok * 8 + (lq & 1) * 4) = pack4(acc);
        }
    }
}

// ---- block-level reduction GEMM (gcon/hcon): M=16 tile from shared bufG,
// f32 out rows 0..NB-1 (verified R15 structure; NW=4 -> waves 0-3, 1 unit).
template <int KT, int NT>
__device__ __forceinline__ void gemmR(const short* __restrict__ wg, int NR,
                                      const short* bG, float* outF,
                                      const float* biasp,
                                      int wave, int lm, int lq) {
    constexpr int NG = (NT + 1) / 2;
    for (int u = wave; u < NG; u += NW) {
        int nt0 = u * 2, nt1 = nt0 + 1;
        bool hasN1 = !((NT & 1) && (u == NG - 1));
        sx8 a0[KT], a1[KT], bfr[KT];
        #pragma unroll
        for (int kt = 0; kt < KT; ++kt) {
            a0[kt] = *(const sx8*)(wg + ((kt * 4 + lq) * NR + nt0 * 16 + lm) * 8);
            bfr[kt] = *(const sx8*)(bG + (kt * 4 + lq) * CHG + lm * 8);
        }
        if (hasN1) {
            #pragma unroll
            for (int kt = 0; kt < KT; ++kt)
                a1[kt] = *(const sx8*)(wg + ((kt * 4 + lq) * NR + nt1 * 16 + lm) * 8);
        }
        int n0l0 = nt0 * 16 + lq * 4;
        int n0l1 = nt1 * 16 + lq * 4;
        fx4 acc0 = *(const fx4*)(biasp + n0l0);
        fx4 acc1;
        if (hasN1) acc1 = *(const fx4*)(biasp + n0l1);
        #pragma unroll
        for (int kt = 0; kt < KT; ++kt) {
            acc0 = __builtin_amdgcn_mfma_f32_16x16x32_bf16(a0[kt], bfr[kt], acc0, 0, 0, 0);
            if (hasN1)
                acc1 = __builtin_amdgcn_mfma_f32_16x16x32_bf16(a1[kt], bfr[kt], acc1, 0, 0, 0);
        }
        if (lm < NB) {
            *(fx4*)(outF + lm * 112 + n0l0) = acc0;
            if (hasN1) *(fx4*)(outF + lm * 112 + n0l1) = acc1;
        }
    }
}

// zero chunks 14,15 of a 16-chunk per-wave region (2 ch x 20 rows = 40 sx8)
__device__ __forceinline__ void zpad2(short* rg, int lane) {
    sx8 z = {0, 0, 0, 0, 0, 0, 0, 0};
    for (int i = lane; i < 40; i += 64)
        *(sx8*)(rg + 14 * CHW + i * 8) = z;
}

__global__ __launch_bounds__(TB, 2) void sp_wave_bf16(
    const float* __restrict__ state,
    const float* __restrict__ m1b0, const float* __restrict__ m1b1,
    const float* __restrict__ m2b0, const float* __restrict__ m2b1,
    const float* __restrict__ atb0, const float* __restrict__ atb1,
    const float* __restrict__ atb2,
    const float* __restrict__ hpb0, const float* __restrict__ hpb1,
    const float* __restrict__ hpb2,
    const short* __restrict__ ws,
    float* __restrict__ out)
{
    __shared__ __align__(16) unsigned char smem[SMEM_BYTES];
    short* bufG  = (short*)(smem + OFF_BUFG);
    float* biasv = (float*)(smem + OFF_BIAS);
    float* rc    = (float*)(smem + OFF_RC);
    float* scv   = (float*)(smem + OFF_SC);
    float* maskv = (float*)(smem + OFF_MASK);

    const int tid  = threadIdx.x;
    const int lane = tid & 63;
    const int wave = tid >> 6;
    const int lm   = lane & 15;
    const int lq   = lane >> 4;
    const int b20  = wave * 20;
    const long gt0 = (long)blockIdx.x * (NB * 20);

    short* act = (short*)(smem + OFF_ACT) + wave * WREG;
    short* R1 = act;                 // 20 ch: t1 -> t2 -> ta -> th
    short* R2 = act + 3200;          // 16 ch: h1 -> ta2 -> th2
    short* R3 = act + 5760;          //  8 ch: x -> h2

    // ---- P1: biases (shared), bufG pad rows 4..15 zero (shared),
    //          mask + x -> R3 (per-wave)
    {
        const float* bs[9] = {m1b0, m1b1, m2b0, m2b1, atb0, atb1, hpb0, hpb1, hpb2};
        const int off[9] = {B_M1B0, B_M1B1, B_M2B0, B_M2B1, B_ATB0, B_ATB1, B_HPB0, B_HPB1, B_HPB2};
        const int sz[9]  = {150, 100, 100, 50, 100, 100, 100, 100, 7};
        const int pd[9]  = {152, 104, 104, 56, 104, 104, 104, 104, 16};
        #pragma unroll
        for (int r = 0; r < 9; ++r)
            for (int i = tid; i < pd[r]; i += TB)
                biasv[off[r] + i] = (i < sz[r]) ? bs[r][i] : 0.f;
        sx8 z = {0, 0, 0, 0, 0, 0, 0, 0};
        for (int t = tid; t < 192; t += TB) {         // (k8, row 4..15)
            int k8 = t / 12, c = 4 + t - (t / 12) * 12;
            *(sx8*)(bufG + (k8 * 16 + c) * 8) = z;
        }
        if (lane < 20)
            maskv[b20 + lane] = state[(gt0 + b20 + lane) * 14 + 13];
        for (int idx = lane; idx < 80; idx += 64) {   // 20 rows x 4 segs
            int row = idx >> 2, seg = idx & 3;
            const float* xp = state + (gt0 + b20 + row) * 14;
            sx8 h;
            #pragma unroll
            for (int i = 0; i < 8; ++i) {
                int k = seg * 8 + i;
                float v = (k < 13) ? xp[k] : 0.f;
                h[i] = f2b(v);
            }
            *(sx8*)(R3 + seg * CHW + row * 8) = h;
        }
    }
    __syncthreads();   // barrier 0: biasv + bufG pad rows visible

    // ---- per-wave chain, no barriers:
    // m1L0 (13->150, relu): x(R3) -> t1(R1)
    wgemm<1, 10, true>(ws + WS_M1W0, 160, R3, R1, biasv + B_M1B0, lm, lq);
    // m1L1 (150->100, relu): t1(R1) -> h1(R2)
    wgemm<5, 7, true>(ws + WS_M1W1, 112, R1, R2, biasv + B_M1B1, lm, lq);
    zpad2(R2, lane);
    // glob (f32 VALU): bufG[.][wave] = sum_t mask[t]*h1[t][j] / msum
    {
        float ms = 0.f;
        #pragma unroll
        for (int t = 0; t < 20; ++t) ms += maskv[b20 + t];
        float inv = (ms > 0.f) ? 1.f / ms : 0.f;
        for (int j = lane; j < 128; j += 64) {
            float g = 0.f;
            if (j < 100) {
                #pragma unroll
                for (int t = 0; t < 20; ++t)
                    g = fmaf(maskv[b20 + t],
                             b2f(R2[(j >> 3) * CHW + t * 8 + (j & 7)]), g);
                g *= inv;
            }
            bufG[(j >> 3) * CHG + wave * 8 + (j & 7)] = f2b(g);
        }
    }
    // m2L0 (100->100, relu): h1(R2) -> t2(R1)
    wgemm<4, 7, true>(ws + WS_M2W0, 112, R2, R1, biasv + B_M2B0, lm, lq);
    zpad2(R1, lane);
    // m2L1 (100->50): t2(R1) -> h2(R3)
    wgemm<4, 4, false>(ws + WS_M2W1, 64, R1, R3, biasv + B_M2B1, lm, lq);
    __syncthreads();   // barrier 1: bufG (glob) complete

    // gcon: rc = atb0 + glob @ atw0[100:200]   (waves 0-3, 1 unit each)
    gemmR<4, 7>(ws + WS_ATW0H, 112, bufG, rc, biasv + B_ATB0, wave, lm, lq);
    __syncthreads();   // barrier 2: rc (grc) visible

    // atL0 (100->100, relu, init=grc row): h1(R2) -> ta(R1)
    wgemm<4, 7, true>(ws + WS_ATW0, 112, R2, R1, rc + wave * 112, lm, lq);
    zpad2(R1, lane);
    // atL1 (100->100, relu): ta(R1) -> ta2(R2)
    wgemm<4, 7, true>(ws + WS_ATW1, 112, R1, R2, biasv + B_ATB1, lm, lq);
    zpad2(R2, lane);
    // scores (per-wave MFMA): ta2 @ atw2 -> scv[b20+tok]
    {
        float atb2s = atb2[0];
        sx8 afr[4];
        #pragma unroll
        for (int kt = 0; kt < 4; ++kt)
            afr[kt] = *(const sx8*)(ws + WS_ATW2 + ((kt * 4 + lq) * 16 + lm) * 8);
        #pragma unroll
        for (int mt = 0; mt < 2; ++mt) {
            int tok = (mt ? 4 : 0) + lm;
            fx4 acc = {0.f, 0.f, 0.f, 0.f};
            const short* bp = R2 + tok * 8;
            #pragma unroll
            for (int kt = 0; kt < 4; ++kt) {
                sx8 b = *(const sx8*)(bp + (kt * 4 + lq) * CHW);
                acc = __builtin_amdgcn_mfma_f32_16x16x32_bf16(afr[kt], b, acc, 0, 0, 0);
            }
            if (lq == 0) {
                float s = (acc[0] + atb2s) * maskv[b20 + tok];
                scv[b20 + tok] = (s != 0.f) ? __expf(s) : 0.f;
            }
        }
    }
    // wsum (f32 VALU): bufG[.][wave] = sum_t se[t]*h2[t][j] / ssum (j<50)
    {
        float ss = 0.f;
        #pragma unroll
        for (int t = 0; t < 20; ++t) ss += scv[b20 + t];
        float inv = (ss > 0.f) ? 1.f / ss : 0.f;
        int j = lane;
        float v = 0.f;
        if (j < 50) {
            #pragma unroll
            for (int t = 0; t < 20; ++t)
                v = fmaf(scv[b20 + t],
                         b2f(R3[(j >> 3) * CHW + t * 8 + (j & 7)]), v);
            v *= inv;
        }
        bufG[(j >> 3) * CHG + wave * 8 + (j & 7)] = f2b(v);
    }
    __syncthreads();   // barrier 3: bufG (wsum) complete

    // hcon: rc = hpb0 + wsum @ hpw0[50:100]   (rc reused; grc dead)
    gemmR<2, 7>(ws + WS_HPW0H, 112, bufG, rc, biasv + B_HPB0, wave, lm, lq);
    __syncthreads();   // barrier 4: rc (wrc) visible

    // hpL0 (50->100, relu, init=wrc row): h2(R3) -> th(R1)
    wgemm<2, 7, true>(ws + WS_HPW0, 112, R3, R1, rc + wave * 112, lm, lq);
    zpad2(R1, lane);
    // hpL1 (100->100, relu): th(R1) -> th2(R2)
    wgemm<4, 7, true>(ws + WS_HPW1, 112, R1, R2, biasv + B_HPB1, lm, lq);
    zpad2(R2, lane);
    // hpL2 (100->7): th2(R2) -> global out (per-wave)
    {
        sx8 afr[4];
        #pragma unroll
        for (int kt = 0; kt < 4; ++kt)
            afr[kt] = *(const sx8*)(ws + WS_HPW2 + ((kt * 4 + lq) * 16 + lm) * 8);
        fx4 ib = *(const fx4*)(biasv + B_HPB2 + lq * 4);
        #pragma unroll
        for (int mt = 0; mt < 2; ++mt) {
            int tok = (mt ? 4 : 0) + lm;
            fx4 acc = ib;
            const short* bp = R2 + tok * 8;
            #pragma unroll
            for (int kt = 0; kt < 4; ++kt) {
                sx8 b = *(const sx8*)(bp + (kt * 4 + lq) * CHW);
                acc = __builtin_amdgcn_mfma_f32_16x16x32_bf16(afr[kt], b, acc, 0, 0, 0);
            }
            if (mt == 0 || lm >= 12) {   // skip duplicate rows 4..15 on mt=1
                #pragma unroll
                for (int r = 0; r < 4; ++r) {
                    int n = lq * 4 + r;
                    if (n < 7) out[(gt0 + b20 + tok) * 7 + n] = acc[r];
                }
            }
        }
    }
}

extern "C" void kernel_launch(void* const* d_in, const int* in_sizes, int n_in,
                              void* d_out, int out_size, void* d_ws, size_t ws_size,
                              hipStream_t stream) {
    int si = 20, wb = 0;
    if (in_sizes[0] > 1000000) { si = 0; wb = 1; }
    const float* state = (const float*)d_in[si];
    const float* W[20];
    for (int i = 0; i < 20; ++i) W[i] = (const float*)d_in[wb + i];
    float* out = (float*)d_out;
    short* ws = (short*)d_ws;
    int Btot = in_sizes[si] / (20 * 14);
    int nblocks = Btot / NB;   // 4 batch elems (4 waves) per block -> 8192

    hipLaunchKernelGGL(stage_weights, dim3(128), dim3(256), 0, stream,
        W[0], W[2], W[4], W[6], W[8], W[10], W[14], W[16], W[18], W[12], ws);

    hipLaunchKernelGGL(sp_wave_bf16, dim3(nblocks), dim3(TB), 0, stream,
        state,
        W[1], W[3],           // m1b0, m1b1
        W[5], W[7],           // m2b0, m2b1
        W[9], W[11],          // atb0, atb1
        W[13],                // atb2
        W[15], W[17], W[19],  // hpb0, hpb1, hpb2
        ws, out);
}

// Round 13
// 419.467 us; speedup vs baseline: 1.3881x; 1.1559x over previous
//
#include <hip/hip_runtime.h>
#include <hip/hip_bf16.h>

// R18: R15 base (best verified: 327us dispatch / 412us bench) + glue merge.
// R17 lesson: per-wave serial chains at 2 waves/SIMD expose latency (-27%);
// R15's 8-wave phase parallelism is the right structure. But R17 PROVED the
// per-wave f32 glue (glob/scores/wsum) correct. R18 keeps all R15 MFMA
// phases and replaces only the glue:
//  (a) mwT build + gemmT glob -> per-wave f32 glob in P4 (wave w: b=w&3,
//      j-half=w>>2), R8-verified formula, alongside m2L0.
//  (b) P8+P9+P10 -> ONE phase: scores (R8-verified 13xsx8 dot, atw2 staged
//      f32 in LDS) on lanes<20; ssum via __shfl; wsum fused same loop
//      (j=half*32+lane, zeros j>=50 = exact P10 output).
// Barriers 13 -> 11; seT rebuild + gemmT transposes gone. f32 glue is more
// precise than the bf16-MFMA path it replaces. Fallback: exact R15.

typedef short sx8 __attribute__((ext_vector_type(8)));
typedef short sx4 __attribute__((ext_vector_type(4)));
typedef float fx4 __attribute__((ext_vector_type(4)));
typedef unsigned ux2 __attribute__((ext_vector_type(2)));

#define TB   512
#define NW   8
#define NB   4      // batch elems per block
#define MTOK 80     // NB*20 tokens
#define MT   5      // m-tiles of 16
#define CHH  640    // halves per k-chunk: MTOK x 8
#define CHG  128    // halves per bufG chunk: 16 tok x 8

// LDS byte offsets (16B aligned)
#define OFF_BUFT 0        // 20 chunks x 1280B = 25600
#define OFF_BUFA 25600    // 16 chunks = 20480
#define OFF_BUFH 46080    // 8 chunks  = 10240
#define OFF_BUFG 56320    // 16 chunks x 256B = 4096
#define OFF_BIAS 60416    // 848 f32 = 3392
#define OFF_GRC  63808    // 4x112 f32 = 1792
#define OFF_WRC  65600    // 4x112 f32 = 1792
#define OFF_MASK 67392    // 80 f32 = 320
#define OFF_MSUM 67712    // 4 f32 (pad 16)
#define OFF_ATW2F 67728   // 104 f32 (pad 448)
#define SMEM_BYTES 68176  // -> 2 blocks/CU

#define B_M1B0 0
#define B_M1B1 152
#define B_M2B0 256
#define B_M2B1 360
#define B_ATB0 416
#define B_ATB1 520
#define B_HPB0 624
#define B_HPB1 728
#define B_HPB2 832

// d_ws offsets in halves; each layer as wA[k8][nl][8]
#define WS_M1W0  0        // KP=32,  NR=160
#define WS_M1W1  5120     // KP=160, NR=112
#define WS_M2W0  23040    // KP=128, NR=112
#define WS_M2W1  37376    // KP=128, NR=64
#define WS_ATW0  45568    // KP=128, NR=112 (rows 0..99)
#define WS_ATW1  59904    // KP=128, NR=112
#define WS_HPW0  74240    // KP=64,  NR=112 (rows 0..49)
#define WS_HPW1  81408    // KP=128, NR=112
#define WS_HPW2  95744    // KP=128, NR=16
#define WS_ATW0H 97792    // KP=128, NR=112 (atw0 rows 100..199)
#define WS_HPW0H 112128   // KP=64,  NR=112 (hpw0 rows 50..99)
#define WS_ATW2  119296   // KP=128, NR=16  (unused by main kernel now)

__device__ __forceinline__ short f2b(float f) {
    unsigned u = __builtin_bit_cast(unsigned, f);
    u += 0x7FFFu + ((u >> 16) & 1u);          // RNE
    return (short)(u >> 16);
}
__device__ __forceinline__ float b2f(short h) {
    unsigned u = ((unsigned)(unsigned short)h) << 16;
    return __builtin_bit_cast(float, u);
}
// 4x f32 -> 4x bf16 via compiler packed cvt (v_cvt_pk_bf16_f32, RNE).
__device__ __forceinline__ sx4 pack4(fx4 v) {
    __hip_bfloat162 lo = __float22bfloat162_rn(make_float2(v[0], v[1]));
    __hip_bfloat162 hi = __float22bfloat162_rn(make_float2(v[2], v[3]));
    ux2 p;
    unsigned ulo, uhi;
    __builtin_memcpy(&ulo, &lo, 4);
    __builtin_memcpy(&uhi, &hi, 4);
    p[0] = ulo; p[1] = uhi;
    return __builtin_bit_cast(sx4, p);
}

// ---- prologue: W[K][N] f32 -> wA[k8][nl][8] bf16 in d_ws (zero padded)
__device__ __forceinline__ void stg(const float* __restrict__ W, int N,
                                    int KR, int KPAD, int NR, int Nsrc,
                                    short* dst, int gtid, int gsz) {
    int K8 = KPAD >> 3;
    for (int idx = gtid; idx < NR * K8; idx += gsz) {
        int k8 = idx / NR, nl = idx - k8 * NR;
        int k0 = k8 << 3;
        sx8 h;
        #pragma unroll
        for (int i = 0; i < 8; ++i) {
            int k = k0 + i;
            float v = (k < KR && nl < Nsrc) ? W[k * N + nl] : 0.f;
            h[i] = f2b(v);
        }
        *(sx8*)(dst + (k8 * NR + nl) * 8) = h;
    }
}

__global__ void stage_weights(
    const float* __restrict__ m1w0, const float* __restrict__ m1w1,
    const float* __restrict__ m2w0, const float* __restrict__ m2w1,
    const float* __restrict__ atw0, const float* __restrict__ atw1,
    const float* __restrict__ hpw0, const float* __restrict__ hpw1,
    const float* __restrict__ hpw2, const float* __restrict__ atw2,
    short* __restrict__ ws)
{
    int gtid = blockIdx.x * blockDim.x + threadIdx.x;
    int gsz = gridDim.x * blockDim.x;
    stg(m1w0, 150, 13, 32, 160, 150, ws + WS_M1W0, gtid, gsz);
    stg(m1w1, 100, 150, 160, 112, 100, ws + WS_M1W1, gtid, gsz);
    stg(m2w0, 100, 100, 128, 112, 100, ws + WS_M2W0, gtid, gsz);
    stg(m2w1, 50, 100, 128, 64, 50, ws + WS_M2W1, gtid, gsz);
    stg(atw0, 100, 100, 128, 112, 100, ws + WS_ATW0, gtid, gsz);
    stg(atw1, 100, 100, 128, 112, 100, ws + WS_ATW1, gtid, gsz);
    stg(hpw0, 100, 50, 64, 112, 100, ws + WS_HPW0, gtid, gsz);
    stg(hpw1, 100, 100, 128, 112, 100, ws + WS_HPW1, gtid, gsz);
    stg(hpw2, 7, 100, 128, 16, 7, ws + WS_HPW2, gtid, gsz);
    stg(atw0 + 100 * 100, 100, 100, 128, 112, 100, ws + WS_ATW0H, gtid, gsz);
    stg(hpw0 + 50 * 100, 100, 50, 64, 112, 100, ws + WS_HPW0H, gtid, gsz);
    stg(atw2, 1, 100, 128, 16, 1, ws + WS_ATW2, gtid, gsz);
}

// ---- main GEMM, NG*2-unit decomposition: unit = (nt-pair, m-half) with
// m-halves {tiles 0-2, tiles 3-4}. For NT=7 this is exactly 8 units ->
// 1 unit/wave. Pad output cols are 0 via zero-padded weights/bias/init.
template <int KT, int NT, bool RELU, bool UINIT>
__device__ __forceinline__ void gemm(const short* __restrict__ wg, int NR,
                                     const short* bIn, short* bOut,
                                     const float* initp, int initBstride,
                                     int wave, int lm, int lq) {
    constexpr int NG = (NT + 1) / 2;
    constexpr int NU = NG * 2;
    for (int u = wave; u < NU; u += NW) {
        int ng = u >> 1, mh = u & 1;
        int nt0 = ng * 2, nt1 = nt0 + 1;
        bool hasN1 = !((NT & 1) && (ng == NG - 1));
        sx8 a0[KT], a1[KT];
        #pragma unroll
        for (int kt = 0; kt < KT; ++kt)
            a0[kt] = *(const sx8*)(wg + ((kt * 4 + lq) * NR + nt0 * 16 + lm) * 8);
        if (hasN1) {
            #pragma unroll
            for (int kt = 0; kt < KT; ++kt)
                a1[kt] = *(const sx8*)(wg + ((kt * 4 + lq) * NR + nt1 * 16 + lm) * 8);
        }
        int n0l0 = nt0 * 16 + lq * 4;
        int n0l1 = nt1 * 16 + lq * 4;
        fx4 ib0, ib1;
        if (UINIT) {
            ib0 = *(const fx4*)(initp + n0l0);
            if (hasN1) ib1 = *(const fx4*)(initp + n0l1);
        }
        int mstart = mh ? 3 : 0;          // MT=5 split {3,2}
        int mcount = mh ? 2 : 3;
        #pragma unroll 3
        for (int mi = 0; mi < mcount; ++mi) {
            int mt = mstart + mi;
            int tok = mt * 16 + lm;
            sx8 bfr[KT];
            #pragma unroll
            for (int kt = 0; kt < KT; ++kt)
                bfr[kt] = *(const sx8*)(bIn + (kt * 4 + lq) * CHH + tok * 8);
            fx4 acc0, acc1;
            if (UINIT) acc0 = ib0;
            else acc0 = *(const fx4*)(initp + (tok / 20) * initBstride + n0l0);
            if (hasN1) {
                if (UINIT) acc1 = ib1;
                else acc1 = *(const fx4*)(initp + (tok / 20) * initBstride + n0l1);
            }
            #pragma unroll
            for (int kt = 0; kt < KT; ++kt) {
                acc0 = __builtin_amdgcn_mfma_f32_16x16x32_bf16(a0[kt], bfr[kt], acc0, 0, 0, 0);
                if (hasN1)
                    acc1 = __builtin_amdgcn_mfma_f32_16x16x32_bf16(a1[kt], bfr[kt], acc1, 0, 0, 0);
            }
            if (RELU) {
                #pragma unroll
                for (int r = 0; r < 4; ++r) acc0[r] = fmaxf(acc0[r], 0.f);
            }
            *(sx4*)(bOut + (nt0 * 2 + (lq >> 1)) * CHH + tok * 8 + (lq & 1) * 4) = pack4(acc0);
            if (hasN1) {
                if (RELU) {
                    #pragma unroll
                    for (int r = 0; r < 4; ++r) acc1[r] = fmaxf(acc1[r], 0.f);
                }
                *(sx4*)(bOut + (nt1 * 2 + (lq >> 1)) * CHH + tok * 8 + (lq & 1) * 4) = pack4(acc1);
            }
        }
    }
}

// ---- reduction GEMM (gcon/hcon): M=16 single tile from bufG, f32 out.
template <int KT, int NT>
__device__ __forceinline__ void gemmR(const short* __restrict__ wg, int NR,
                                      const short* bG, float* outF,
                                      const float* biasp,
                                      int wave, int lm, int lq) {
    constexpr int NG = (NT + 1) / 2;
    for (int u = wave; u < NG; u += NW) {
        int nt0 = u * 2, nt1 = nt0 + 1;
        bool hasN1 = !((NT & 1) && (u == NG - 1));
        sx8 a0[KT], a1[KT], bfr[KT];
        #pragma unroll
        for (int kt = 0; kt < KT; ++kt) {
            a0[kt] = *(const sx8*)(wg + ((kt * 4 + lq) * NR + nt0 * 16 + lm) * 8);
            bfr[kt] = *(const sx8*)(bG + (kt * 4 + lq) * CHG + lm * 8);
        }
        if (hasN1) {
            #pragma unroll
            for (int kt = 0; kt < KT; ++kt)
                a1[kt] = *(const sx8*)(wg + ((kt * 4 + lq) * NR + nt1 * 16 + lm) * 8);
        }
        int n0l0 = nt0 * 16 + lq * 4;
        int n0l1 = nt1 * 16 + lq * 4;
        fx4 acc0 = *(const fx4*)(biasp + n0l0);
        fx4 acc1;
        if (hasN1) acc1 = *(const fx4*)(biasp + n0l1);
        #pragma unroll
        for (int kt = 0; kt < KT; ++kt) {
            acc0 = __builtin_amdgcn_mfma_f32_16x16x32_bf16(a0[kt], bfr[kt], acc0, 0, 0, 0);
            if (hasN1)
                acc1 = __builtin_amdgcn_mfma_f32_16x16x32_bf16(a1[kt], bfr[kt], acc1, 0, 0, 0);
        }
        if (lm < NB) {
            *(fx4*)(outF + lm * 112 + n0l0) = acc0;
            if (hasN1) *(fx4*)(outF + lm * 112 + n0l1) = acc1;
        }
    }
}

// zero chunks 14,15 of a 16-chunk activation buffer
__device__ __forceinline__ void zpad(short* buf, int tid) {
    for (int i = tid; i < 160; i += TB) {
        sx8 z = {0, 0, 0, 0, 0, 0, 0, 0};
        *(sx8*)(buf + 14 * CHH + i * 8) = z;
    }
}

__global__ __launch_bounds__(TB, 4) void sp_mfma_bf16(
    const float* __restrict__ state,
    const float* __restrict__ m1b0, const float* __restrict__ m1b1,
    const float* __restrict__ m2b0, const float* __restrict__ m2b1,
    const float* __restrict__ atb0, const float* __restrict__ atb1,
    const float* __restrict__ atb2, const float* __restrict__ atw2,
    const float* __restrict__ hpb0, const float* __restrict__ hpb1,
    const float* __restrict__ hpb2,
    const short* __restrict__ ws,
    float* __restrict__ out)
{
    __shared__ __align__(16) unsigned char smem[SMEM_BYTES];
    short* bufT  = (short*)(smem + OFF_BUFT);
    short* bufA  = (short*)(smem + OFF_BUFA);
    short* bufH2 = (short*)(smem + OFF_BUFH);
    short* bufG  = (short*)(smem + OFF_BUFG);
    float* biasv = (float*)(smem + OFF_BIAS);
    float* grc   = (float*)(smem + OFF_GRC);
    float* wrc   = (float*)(smem + OFF_WRC);
    float* maskv = (float*)(smem + OFF_MASK);
    float* msum  = (float*)(smem + OFF_MSUM);
    float* atw2f = (float*)(smem + OFF_ATW2F);

    const int tid  = threadIdx.x;
    const int lane = tid & 63;
    const int wave = tid >> 6;
    const int lm   = lane & 15;
    const int lq   = lane >> 4;
    const long gt0 = (long)blockIdx.x * MTOK;

    // ---- P1: biases, mask, atw2 (f32), x -> bufA chunks 0..3, bufG zero
    {
        const float* bs[9] = {m1b0, m1b1, m2b0, m2b1, atb0, atb1, hpb0, hpb1, hpb2};
        const int off[9] = {B_M1B0, B_M1B1, B_M2B0, B_M2B1, B_ATB0, B_ATB1, B_HPB0, B_HPB1, B_HPB2};
        const int sz[9]  = {150, 100, 100, 50, 100, 100, 100, 100, 7};
        const int pd[9]  = {152, 104, 104, 56, 104, 104, 104, 104, 16};
        #pragma unroll
        for (int r = 0; r < 9; ++r)
            for (int i = tid; i < pd[r]; i += TB)
                biasv[off[r] + i] = (i < sz[r]) ? bs[r][i] : 0.f;
        for (int i = tid; i < 104; i += TB)
            atw2f[i] = (i < 100) ? atw2[i] : 0.f;
        if (tid < MTOK) maskv[tid] = state[(gt0 + tid) * 14 + 13];
        for (int t = tid; t < 256; t += TB) {
            sx8 z = {0, 0, 0, 0, 0, 0, 0, 0};
            *(sx8*)(bufG + t * 8) = z;
        }
        for (int idx = tid; idx < MTOK * 4; idx += TB) {
            int row = idx >> 2, seg = idx & 3;
            const float* xp = state + (gt0 + row) * 14;
            sx8 h;
            #pragma unroll
            for (int i = 0; i < 8; ++i) {
                int k = seg * 8 + i;
                float v = (k < 13) ? xp[k] : 0.f;
                h[i] = f2b(v);
            }
            *(sx8*)(bufA + seg * CHH + row * 8) = h;
        }
    }
    __syncthreads();

    // ---- P2: msum + m1L0 (13->150, relu): x(bufA) -> bufT
    if (tid < NB) {
        float s = 0.f;
        #pragma unroll
        for (int n = 0; n < 20; ++n) s += maskv[tid * 20 + n];
        msum[tid] = s;
    }
    gemm<1, 10, true, true>(ws + WS_M1W0, 160, bufA, bufT, biasv + B_M1B0, 0,
                            wave, lm, lq);
    __syncthreads();

    // ---- P3: m1L1 (150->100, relu): bufT -> bufA (h1)
    gemm<5, 7, true, true>(ws + WS_M1W1, 112, bufT, bufA, biasv + B_M1B1, 0,
                           wave, lm, lq);
    zpad(bufA, tid);
    __syncthreads();

    // ---- P4: glob (per-wave f32: wave w -> b=w&3, j-half=w>>2)
    //          + m2L0 (100->100, relu): h1(bufA) -> bufT
    {
        int b = wave & 3, half = wave >> 2;
        int j = half * 64 + lane;
        if (j < 112) {
            float g = 0.f;
            if (j < 100) {
                float ms = msum[b];
                float inv = (ms > 0.f) ? 1.f / ms : 0.f;
                const short* hp = bufA + (j >> 3) * CHH + (j & 7);
                #pragma unroll
                for (int t = 0; t < 20; ++t)
                    g = fmaf(maskv[b * 20 + t], b2f(hp[(b * 20 + t) * 8]), g);
                g *= inv;
            }
            bufG[(j >> 3) * CHG + b * 8 + (j & 7)] = f2b(g);
        }
    }
    gemm<4, 7, true, true>(ws + WS_M2W0, 112, bufA, bufT, biasv + B_M2B0, 0,
                           wave, lm, lq);
    zpad(bufT, tid);
    __syncthreads();

    // ---- P5: gcon (gemmR, waves 0-3) + m2L1 (100->50, waves 4-7)
    gemmR<4, 7>(ws + WS_ATW0H, 112, bufG, grc, biasv + B_ATB0, wave, lm, lq);
    gemm<4, 4, false, true>(ws + WS_M2W1, 64, bufT, bufH2, biasv + B_M2B1, 0,
                            (wave + 4) & 7, lm, lq);
    __syncthreads();

    // ---- P6: atL0 (100->100, relu, init=gcon): h1(bufA) -> bufT
    gemm<4, 7, true, false>(ws + WS_ATW0, 112, bufA, bufT, grc, 112,
                            wave, lm, lq);
    __syncthreads();

    // ---- P7: atL1 (100->100, relu): bufT -> bufA (ta2)
    gemm<4, 7, true, true>(ws + WS_ATW1, 112, bufT, bufA, biasv + B_ATB1, 0,
                           wave, lm, lq);
    __syncthreads();

    // ---- P8: merged scores + ssum + wsum (per-wave: b=w&3, half=w>>2)
    {
        int b = wave & 3, half = wave >> 2;
        int tokb = b * 20;
        float atb2s = atb2[0];
        float se = 0.f;
        if (lane < 20) {
            float s = atb2s;
            const short* bp = bufA + (tokb + lane) * 8;
            #pragma unroll
            for (int k8 = 0; k8 < 13; ++k8) {
                sx8 v = *(const sx8*)(bp + k8 * CHH);
                #pragma unroll
                for (int i = 0; i < 8; ++i)
                    s = fmaf(b2f(v[i]), atw2f[k8 * 8 + i], s);
            }
            s *= maskv[tokb + lane];
            se = (s != 0.f) ? __expf(s) : 0.f;
        }
        // wsum: j = half*32 + lane (lanes 0-31), covers j 0..63 (0 for j>=50)
        int j = half * 32 + (lane & 31);
        bool act = (lane < 32);
        float ss = 0.f, v = 0.f;
        const short* hp = bufH2 + (j >> 3) * CHH + (j & 7);
        #pragma unroll
        for (int t = 0; t < 20; ++t) {
            float set = __shfl(se, t, 64);
            ss += set;
            if (act && j < 50)
                v = fmaf(set, b2f(hp[(tokb + t) * 8]), v);
        }
        if (act) {
            float inv = (ss > 0.f) ? 1.f / ss : 0.f;
            bufG[(j >> 3) * CHG + b * 8 + (j & 7)] = f2b((j < 50) ? v * inv : 0.f);
        }
    }
    __syncthreads();

    // ---- P11: hcon (gemmR: wrc = hpb0 + wsum @ hpw0[50:100])
    gemmR<2, 7>(ws + WS_HPW0H, 112, bufG, wrc, biasv + B_HPB0, wave, lm, lq);
    __syncthreads();

    // ---- P12: hpL0 (50->100, relu, init=hcon): h2(bufH2) -> bufT
    gemm<2, 7, true, false>(ws + WS_HPW0, 112, bufH2, bufT, wrc, 112,
                            wave, lm, lq);
    __syncthreads();

    // ---- P13: hpL1 (100->100, relu): bufT -> bufA
    gemm<4, 7, true, true>(ws + WS_HPW1, 112, bufT, bufA, biasv + B_HPB1, 0,
                           wave, lm, lq);
    __syncthreads();

    // ---- P14: hpL2 (100->7) -> global out; A-frags hoisted
    {
        sx8 afr[4];
        #pragma unroll
        for (int kt = 0; kt < 4; ++kt)
            afr[kt] = *(const sx8*)(ws + WS_HPW2 + ((kt * 4 + lq) * 16 + lm) * 8);
        fx4 ib = *(const fx4*)(biasv + B_HPB2 + lq * 4);
        for (int mt = wave; mt < MT; mt += NW) {
            int tok = mt * 16 + lm;
            fx4 acc = ib;
            const short* bp = bufA + tok * 8;
            #pragma unroll
            for (int kt = 0; kt < 4; ++kt) {
                sx8 b = *(const sx8*)(bp + (kt * 4 + lq) * CHH);
                acc = __builtin_amdgcn_mfma_f32_16x16x32_bf16(afr[kt], b, acc, 0, 0, 0);
            }
            #pragma unroll
            for (int r = 0; r < 4; ++r) {
                int n = lq * 4 + r;
                if (n < 7) out[(gt0 + tok) * 7 + n] = acc[r];
            }
        }
    }
}

extern "C" void kernel_launch(void* const* d_in, const int* in_sizes, int n_in,
                              void* d_out, int out_size, void* d_ws, size_t ws_size,
                              hipStream_t stream) {
    int si = 20, wb = 0;
    if (in_sizes[0] > 1000000) { si = 0; wb = 1; }
    const float* state = (const float*)d_in[si];
    const float* W[20];
    for (int i = 0; i < 20; ++i) W[i] = (const float*)d_in[wb + i];
    float* out = (float*)d_out;
    short* ws = (short*)d_ws;
    int Btot = in_sizes[si] / (20 * 14);
    int nblocks = Btot / NB;   // 4 b's (80 tokens) per block -> 8192

    hipLaunchKernelGGL(stage_weights, dim3(128), dim3(256), 0, stream,
        W[0], W[2], W[4], W[6], W[8], W[10], W[14], W[16], W[18], W[12], ws);

    hipLaunchKernelGGL(sp_mfma_bf16, dim3(nblocks), dim3(TB), 0, stream,
        state,
        W[1], W[3],           // m1b0, m1b1
        W[5], W[7],           // m2b0, m2b1
        W[9], W[11],          // atb0, atb1
        W[13], W[12],         // atb2, atw2
        W[15], W[17], W[19],  // hpb0, hpb1, hpb2
        ws, out);
}

// Round 14
// 417.522 us; speedup vs baseline: 1.3946x; 1.0047x over previous
//
#include <hip/hip_runtime.h>
#include <hip/hip_bf16.h>

// R19: R15 exact base (best verified: 327us dispatch / 412us bench, absmax
// 0.0068) + depth-1 A-frag software pipelining. R18's phase-merge was
// neutral (glue wasn't critical path) -> reverted. Measured model: each
// phase pays ~200-400cy A-frag (global ws, L2) lead-in after its barrier
// before the first MFMA. Fix: issue NEXT phase's A-loads at the START of
// the current phase (loadApair into named regs), consume via gemmP/gemmRP.
// Bit-identical arithmetic; only load placement changes. VGPR 52 -> ~95
// (peak two frag sets live), safely under the 128 cap of bounds(512,4).
// Prefetched: P4,P5(R+g),P6,P7,P8(afr),P11,P12,P13,P14. P2/P3 inline.

typedef short sx8 __attribute__((ext_vector_type(8)));
typedef short sx4 __attribute__((ext_vector_type(4)));
typedef float fx4 __attribute__((ext_vector_type(4)));
typedef unsigned ux2 __attribute__((ext_vector_type(2)));

#define TB   512
#define NW   8
#define NB   4      // batch elems per block
#define MTOK 80     // NB*20 tokens
#define MT   5      // m-tiles of 16
#define CHH  640    // halves per k-chunk: MTOK x 8
#define CHG  128    // halves per bufG chunk: 16 tok x 8

// LDS byte offsets (16B aligned)
#define OFF_BUFT 0        // 20 chunks x 1280B = 25600
#define OFF_BUFA 25600    // 16 chunks = 20480
#define OFF_BUFH 46080    // 8 chunks  = 10240
#define OFF_BUFG 56320    // 16 chunks x 256B = 4096
#define OFF_BIAS 60416    // 848 f32 = 3392
#define OFF_GRC  63808    // 4x112 f32 = 1792
#define OFF_WRC  65600    // 4x112 f32 = 1792
#define OFF_SC   67392    // 80 f32 (pad 320)
#define OFF_MASK 67712    // 80 f32 (pad 320)
#define OFF_MSUM 68032    // 4 f32 (pad 16)
#define OFF_WTM  68048    // 16x96 bf16 = 3072 (mwT, then seT)
#define SMEM_BYTES 71120  // -> 2 blocks/CU (<= 80KB)

#define B_M1B0 0
#define B_M1B1 152
#define B_M2B0 256
#define B_M2B1 360
#define B_ATB0 416
#define B_ATB1 520
#define B_HPB0 624
#define B_HPB1 728
#define B_HPB2 832

// d_ws offsets in halves; each layer as wA[k8][nl][8]
#define WS_M1W0  0        // KP=32,  NR=160
#define WS_M1W1  5120     // KP=160, NR=112
#define WS_M2W0  23040    // KP=128, NR=112
#define WS_M2W1  37376    // KP=128, NR=64
#define WS_ATW0  45568    // KP=128, NR=112 (rows 0..99)
#define WS_ATW1  59904    // KP=128, NR=112
#define WS_HPW0  74240    // KP=64,  NR=112 (rows 0..49)
#define WS_HPW1  81408    // KP=128, NR=112
#define WS_HPW2  95744    // KP=128, NR=16
#define WS_ATW0H 97792    // KP=128, NR=112 (atw0 rows 100..199)
#define WS_HPW0H 112128   // KP=64,  NR=112 (hpw0 rows 50..99)
#define WS_ATW2  119296   // KP=128, NR=16  (atw2 as 100x1, row 0)

__device__ __forceinline__ short f2b(float f) {
    unsigned u = __builtin_bit_cast(unsigned, f);
    u += 0x7FFFu + ((u >> 16) & 1u);          // RNE
    return (short)(u >> 16);
}
__device__ __forceinline__ float b2f(short h) {
    unsigned u = ((unsigned)(unsigned short)h) << 16;
    return __builtin_bit_cast(float, u);
}
// 4x f32 -> 4x bf16 via compiler packed cvt (v_cvt_pk_bf16_f32, RNE).
__device__ __forceinline__ sx4 pack4(fx4 v) {
    __hip_bfloat162 lo = __float22bfloat162_rn(make_float2(v[0], v[1]));
    __hip_bfloat162 hi = __float22bfloat162_rn(make_float2(v[2], v[3]));
    ux2 p;
    unsigned ulo, uhi;
    __builtin_memcpy(&ulo, &lo, 4);
    __builtin_memcpy(&uhi, &hi, 4);
    p[0] = ulo; p[1] = uhi;
    return __builtin_bit_cast(sx4, p);
}

// ---- prologue: W[K][N] f32 -> wA[k8][nl][8] bf16 in d_ws (zero padded)
__device__ __forceinline__ void stg(const float* __restrict__ W, int N,
                                    int KR, int KPAD, int NR, int Nsrc,
                                    short* dst, int gtid, int gsz) {
    int K8 = KPAD >> 3;
    for (int idx = gtid; idx < NR * K8; idx += gsz) {
        int k8 = idx / NR, nl = idx - k8 * NR;
        int k0 = k8 << 3;
        sx8 h;
        #pragma unroll
        for (int i = 0; i < 8; ++i) {
            int k = k0 + i;
            float v = (k < KR && nl < Nsrc) ? W[k * N + nl] : 0.f;
            h[i] = f2b(v);
        }
        *(sx8*)(dst + (k8 * NR + nl) * 8) = h;
    }
}

__global__ void stage_weights(
    const float* __restrict__ m1w0, const float* __restrict__ m1w1,
    const float* __restrict__ m2w0, const float* __restrict__ m2w1,
    const float* __restrict__ atw0, const float* __restrict__ atw1,
    const float* __restrict__ hpw0, const float* __restrict__ hpw1,
    const float* __restrict__ hpw2, const float* __restrict__ atw2,
    short* __restrict__ ws)
{
    int gtid = blockIdx.x * blockDim.x + threadIdx.x;
    int gsz = gridDim.x * blockDim.x;
    stg(m1w0, 150, 13, 32, 160, 150, ws + WS_M1W0, gtid, gsz);
    stg(m1w1, 100, 150, 160, 112, 100, ws + WS_M1W1, gtid, gsz);
    stg(m2w0, 100, 100, 128, 112, 100, ws + WS_M2W0, gtid, gsz);
    stg(m2w1, 50, 100, 128, 64, 50, ws + WS_M2W1, gtid, gsz);
    stg(atw0, 100, 100, 128, 112, 100, ws + WS_ATW0, gtid, gsz);
    stg(atw1, 100, 100, 128, 112, 100, ws + WS_ATW1, gtid, gsz);
    stg(hpw0, 100, 50, 64, 112, 100, ws + WS_HPW0, gtid, gsz);
    stg(hpw1, 100, 100, 128, 112, 100, ws + WS_HPW1, gtid, gsz);
    stg(hpw2, 7, 100, 128, 16, 7, ws + WS_HPW2, gtid, gsz);
    stg(atw0 + 100 * 100, 100, 100, 128, 112, 100, ws + WS_ATW0H, gtid, gsz);
    stg(hpw0 + 50 * 100, 100, 50, 64, 112, 100, ws + WS_HPW0H, gtid, gsz);
    stg(atw2, 1, 100, 128, 16, 1, ws + WS_ATW2, gtid, gsz);
}

// ---- A-frag pair loader (prefetch): nt0/hasN1 computed by caller.
template <int KT>
__device__ __forceinline__ void loadApair(const short* __restrict__ wg, int NR,
                                          int nt0, bool hasN1, int lm, int lq,
                                          sx8* a0, sx8* a1) {
    #pragma unroll
    for (int kt = 0; kt < KT; ++kt)
        a0[kt] = *(const sx8*)(wg + ((kt * 4 + lq) * NR + nt0 * 16 + lm) * 8);
    if (hasN1) {
        #pragma unroll
        for (int kt = 0; kt < KT; ++kt)
            a1[kt] = *(const sx8*)(wg + ((kt * 4 + lq) * NR + (nt0 + 1) * 16 + lm) * 8);
    }
}

// ---- main GEMM (inline-A version; R15-verified NG*2 decomposition)
template <int KT, int NT, bool RELU, bool UINIT>
__device__ __forceinline__ void gemm(const short* __restrict__ wg, int NR,
                                     const short* bIn, short* bOut,
                                     const float* initp, int initBstride,
                                     int wave, int lm, int lq) {
    constexpr int NG = (NT + 1) / 2;
    constexpr int NU = NG * 2;
    for (int u = wave; u < NU; u += NW) {
        int ng = u >> 1, mh = u & 1;
        int nt0 = ng * 2, nt1 = nt0 + 1;
        bool hasN1 = !((NT & 1) && (ng == NG - 1));
        sx8 a0[KT], a1[KT];
        #pragma unroll
        for (int kt = 0; kt < KT; ++kt)
            a0[kt] = *(const sx8*)(wg + ((kt * 4 + lq) * NR + nt0 * 16 + lm) * 8);
        if (hasN1) {
            #pragma unroll
            for (int kt = 0; kt < KT; ++kt)
                a1[kt] = *(const sx8*)(wg + ((kt * 4 + lq) * NR + nt1 * 16 + lm) * 8);
        }
        int n0l0 = nt0 * 16 + lq * 4;
        int n0l1 = nt1 * 16 + lq * 4;
        fx4 ib0, ib1;
        if (UINIT) {
            ib0 = *(const fx4*)(initp + n0l0);
            if (hasN1) ib1 = *(const fx4*)(initp + n0l1);
        }
        int mstart = mh ? 3 : 0;          // MT=5 split {3,2}
        int mcount = mh ? 2 : 3;
        #pragma unroll 3
        for (int mi = 0; mi < mcount; ++mi) {
            int mt = mstart + mi;
            int tok = mt * 16 + lm;
            sx8 bfr[KT];
            #pragma unroll
            for (int kt = 0; kt < KT; ++kt)
                bfr[kt] = *(const sx8*)(bIn + (kt * 4 + lq) * CHH + tok * 8);
            fx4 acc0, acc1;
            if (UINIT) acc0 = ib0;
            else acc0 = *(const fx4*)(initp + (tok / 20) * initBstride + n0l0);
            if (hasN1) {
                if (UINIT) acc1 = ib1;
                else acc1 = *(const fx4*)(initp + (tok / 20) * initBstride + n0l1);
            }
            #pragma unroll
            for (int kt = 0; kt < KT; ++kt) {
                acc0 = __builtin_amdgcn_mfma_f32_16x16x32_bf16(a0[kt], bfr[kt], acc0, 0, 0, 0);
                if (hasN1)
                    acc1 = __builtin_amdgcn_mfma_f32_16x16x32_bf16(a1[kt], bfr[kt], acc1, 0, 0, 0);
            }
            if (RELU) {
                #pragma unroll
                for (int r = 0; r < 4; ++r) acc0[r] = fmaxf(acc0[r], 0.f);
            }
            *(sx4*)(bOut + (nt0 * 2 + (lq >> 1)) * CHH + tok * 8 + (lq & 1) * 4) = pack4(acc0);
            if (hasN1) {
                if (RELU) {
                    #pragma unroll
                    for (int r = 0; r < 4; ++r) acc1[r] = fmaxf(acc1[r], 0.f);
                }
                *(sx4*)(bOut + (nt1 * 2 + (lq >> 1)) * CHH + tok * 8 + (lq & 1) * 4) = pack4(acc1);
            }
        }
    }
}

// ---- gemm with PRELOADED A-frags (u = this wave's unit; body verbatim)
template <int KT, int NT, bool RELU, bool UINIT>
__device__ __forceinline__ void gemmP(const sx8* a0, const sx8* a1,
                                      const short* bIn, short* bOut,
                                      const float* initp, int initBstride,
                                      int u, int lm, int lq) {
    constexpr int NG = (NT + 1) / 2;
    constexpr int NU = NG * 2;
    if (u >= NU) return;
    int ng = u >> 1, mh = u & 1;
    int nt0 = ng * 2, nt1 = nt0 + 1;
    bool hasN1 = !((NT & 1) && (ng == NG - 1));
    int n0l0 = nt0 * 16 + lq * 4;
    int n0l1 = nt1 * 16 + lq * 4;
    fx4 ib0, ib1;
    if (UINIT) {
        ib0 = *(const fx4*)(initp + n0l0);
        if (hasN1) ib1 = *(const fx4*)(initp + n0l1);
    }
    int mstart = mh ? 3 : 0;
    int mcount = mh ? 2 : 3;
    #pragma unroll 3
    for (int mi = 0; mi < mcount; ++mi) {
        int mt = mstart + mi;
        int tok = mt * 16 + lm;
        sx8 bfr[KT];
        #pragma unroll
        for (int kt = 0; kt < KT; ++kt)
            bfr[kt] = *(const sx8*)(bIn + (kt * 4 + lq) * CHH + tok * 8);
        fx4 acc0, acc1;
        if (UINIT) acc0 = ib0;
        else acc0 = *(const fx4*)(initp + (tok / 20) * initBstride + n0l0);
        if (hasN1) {
            if (UINIT) acc1 = ib1;
            else acc1 = *(const fx4*)(initp + (tok / 20) * initBstride + n0l1);
        }
        #pragma unroll
        for (int kt = 0; kt < KT; ++kt) {
            acc0 = __builtin_amdgcn_mfma_f32_16x16x32_bf16(a0[kt], bfr[kt], acc0, 0, 0, 0);
            if (hasN1)
                acc1 = __builtin_amdgcn_mfma_f32_16x16x32_bf16(a1[kt], bfr[kt], acc1, 0, 0, 0);
        }
        if (RELU) {
            #pragma unroll
            for (int r = 0; r < 4; ++r) acc0[r] = fmaxf(acc0[r], 0.f);
        }
        *(sx4*)(bOut + (nt0 * 2 + (lq >> 1)) * CHH + tok * 8 + (lq & 1) * 4) = pack4(acc0);
        if (hasN1) {
            if (RELU) {
                #pragma unroll
                for (int r = 0; r < 4; ++r) acc1[r] = fmaxf(acc1[r], 0.f);
            }
            *(sx4*)(bOut + (nt1 * 2 + (lq >> 1)) * CHH + tok * 8 + (lq & 1) * 4) = pack4(acc1);
        }
    }
}

// ---- reduction GEMM with preloaded A (gcon/hcon; u = wave, waves < NG)
template <int KT, int NT>
__device__ __forceinline__ void gemmRP(const sx8* a0, const sx8* a1,
                                       const short* bG, float* outF,
                                       const float* biasp, int u, int lm, int lq) {
    constexpr int NG = (NT + 1) / 2;
    if (u >= NG) return;
    int nt0 = u * 2, nt1 = nt0 + 1;
    bool hasN1 = !((NT & 1) && (u == NG - 1));
    sx8 bfr[KT];
    #pragma unroll
    for (int kt = 0; kt < KT; ++kt)
        bfr[kt] = *(const sx8*)(bG + (kt * 4 + lq) * CHG + lm * 8);
    int n0l0 = nt0 * 16 + lq * 4;
    int n0l1 = nt1 * 16 + lq * 4;
    fx4 acc0 = *(const fx4*)(biasp + n0l0);
    fx4 acc1;
    if (hasN1) acc1 = *(const fx4*)(biasp + n0l1);
    #pragma unroll
    for (int kt = 0; kt < KT; ++kt) {
        acc0 = __builtin_amdgcn_mfma_f32_16x16x32_bf16(a0[kt], bfr[kt], acc0, 0, 0, 0);
        if (hasN1)
            acc1 = __builtin_amdgcn_mfma_f32_16x16x32_bf16(a1[kt], bfr[kt], acc1, 0, 0, 0);
    }
    if (lm < NB) {
        *(fx4*)(outF + lm * 112 + n0l0) = acc0;
        if (hasN1) *(fx4*)(outF + lm * 112 + n0l1) = acc1;
    }
}

// ---- transposed-A reduction GEMM (glob/wsum): R15-verified, unchanged.
template <int NT>
__device__ __forceinline__ void gemmT(const short* __restrict__ act,
                                      const short* __restrict__ wT,
                                      short* __restrict__ bG,
                                      int wave, int lm, int lq) {
    for (int nt = wave; nt < NT; nt += NW) {
        int j = nt * 16 + lm;
        const short* ap = act + (j >> 3) * CHH + (j & 7);
        fx4 acc = {0.f, 0.f, 0.f, 0.f};
        #pragma unroll
        for (int kt = 0; kt < 3; ++kt) {
            int tok0 = kt * 32 + lq * 8;
            int tok0e = (tok0 < MTOK) ? tok0 : 0;  // rows >= 80 are zero in wT
            sx8 a;
            #pragma unroll
            for (int i = 0; i < 8; ++i) {
                int ii = (i + lq * 2) & 7;         // bank-staggered K permute
                a[i] = ap[(tok0e + ii) * 8];
            }
            sx8 b = *(const sx8*)(wT + lm * 96 + tok0);
            acc = __builtin_amdgcn_mfma_f32_16x16x32_bf16(a, b, acc, 0, 0, 0);
        }
        if (lm < NB) {   // D[row=j][col=b]; only b<NB real
            *(sx4*)(bG + (nt * 2 + (lq >> 1)) * CHG + lm * 8 + (lq & 1) * 4) = pack4(acc);
        }
    }
}

// zero chunks 14,15 of a 16-chunk activation buffer
__device__ __forceinline__ void zpad(short* buf, int tid) {
    for (int i = tid; i < 160; i += TB) {
        sx8 z = {0, 0, 0, 0, 0, 0, 0, 0};
        *(sx8*)(buf + 14 * CHH + i * 8) = z;
    }
}

__global__ __launch_bounds__(TB, 4) void sp_mfma_bf16(
    const float* __restrict__ state,
    const float* __restrict__ m1b0, const float* __restrict__ m1b1,
    const float* __restrict__ m2b0, const float* __restrict__ m2b1,
    const float* __restrict__ atb0, const float* __restrict__ atb1,
    const float* __restrict__ atb2,
    const float* __restrict__ hpb0, const float* __restrict__ hpb1,
    const float* __restrict__ hpb2,
    const short* __restrict__ ws,
    float* __restrict__ out)
{
    __shared__ __align__(16) unsigned char smem[SMEM_BYTES];
    short* bufT  = (short*)(smem + OFF_BUFT);
    short* bufA  = (short*)(smem + OFF_BUFA);
    short* bufH2 = (short*)(smem + OFF_BUFH);
    short* bufG  = (short*)(smem + OFF_BUFG);
    float* biasv = (float*)(smem + OFF_BIAS);
    float* grc   = (float*)(smem + OFF_GRC);
    float* wrc   = (float*)(smem + OFF_WRC);
    float* scv   = (float*)(smem + OFF_SC);
    float* maskv = (float*)(smem + OFF_MASK);
    float* msum  = (float*)(smem + OFF_MSUM);
    short* wTm   = (short*)(smem + OFF_WTM);

    const int tid  = threadIdx.x;
    const int lane = tid & 63;
    const int wave = tid >> 6;
    const int lm   = lane & 15;
    const int lq   = lane >> 4;
    const long gt0 = (long)blockIdx.x * MTOK;

    // gemm-style unit mapping for this wave (NT=7): ng, hasN1
    const int png   = wave >> 1;
    const bool ph1  = (png != 3);          // hasN1 for NT=7

    // ---- P1: biases, mask, x -> bufA chunks 0..3, bufG zero-init
    {
        const float* bs[9] = {m1b0, m1b1, m2b0, m2b1, atb0, atb1, hpb0, hpb1, hpb2};
        const int off[9] = {B_M1B0, B_M1B1, B_M2B0, B_M2B1, B_ATB0, B_ATB1, B_HPB0, B_HPB1, B_HPB2};
        const int sz[9]  = {150, 100, 100, 50, 100, 100, 100, 100, 7};
        const int pd[9]  = {152, 104, 104, 56, 104, 104, 104, 104, 16};
        #pragma unroll
        for (int r = 0; r < 9; ++r)
            for (int i = tid; i < pd[r]; i += TB)
                biasv[off[r] + i] = (i < sz[r]) ? bs[r][i] : 0.f;
        if (tid < MTOK) maskv[tid] = state[(gt0 + tid) * 14 + 13];
        for (int t = tid; t < 256; t += TB) {
            sx8 z = {0, 0, 0, 0, 0, 0, 0, 0};
            *(sx8*)(bufG + t * 8) = z;
        }
        for (int idx = tid; idx < MTOK * 4; idx += TB) {
            int row = idx >> 2, seg = idx & 3;
            const float* xp = state + (gt0 + row) * 14;
            sx8 h;
            #pragma unroll
            for (int i = 0; i < 8; ++i) {
                int k = seg * 8 + i;
                float v = (k < 13) ? xp[k] : 0.f;
                h[i] = f2b(v);
            }
            *(sx8*)(bufA + seg * CHH + row * 8) = h;
        }
    }
    __syncthreads();

    // ---- P2: msum + m1L0 (13->150, relu): x(bufA) -> bufT  (inline A)
    if (tid < NB) {
        float s = 0.f;
        #pragma unroll
        for (int n = 0; n < 20; ++n) s += maskv[tid * 20 + n];
        msum[tid] = s;
    }
    gemm<1, 10, true, true>(ws + WS_M1W0, 160, bufA, bufT, biasv + B_M1B0, 0,
                            wave, lm, lq);
    __syncthreads();

    // ---- P3: [prefetch A4=M2W0] m1L1 (150->100, relu) + mwT build
    sx8 a4_0[4], a4_1[4];
    loadApair<4>(ws + WS_M2W0, 112, png * 2, ph1, lm, lq, a4_0, a4_1);
    gemm<5, 7, true, true>(ws + WS_M1W1, 112, bufT, bufA, biasv + B_M1B1, 0,
                           wave, lm, lq);
    zpad(bufA, tid);
    for (int t = tid; t < 1536; t += TB) {       // mwT[b][tperm], 16x96
        int b = t / 96, tp = t - b * 96;
        int tau = (tp & ~7) | ((tp + ((tp >> 3) & 3) * 2) & 7);
        float v = 0.f;
        if (b < NB && tau < MTOK && tau / 20 == b) {
            float ms = msum[b];
            v = (ms > 0.f) ? maskv[tau] / ms : 0.f;
        }
        wTm[t] = f2b(v);
    }
    __syncthreads();

    // ---- P4: [prefetch A5: waves0-3 ATW0H(gemmR), waves4-7 M2W1(gemm<4,4>)]
    //          glob (gemmT) + m2L0 (gemmP A4)
    sx8 a5_0[4], a5_1[4];
    if (wave < 4)
        loadApair<4>(ws + WS_ATW0H, 112, wave * 2, wave != 3, lm, lq, a5_0, a5_1);
    else
        loadApair<4>(ws + WS_M2W1, 64, ((wave - 4) >> 1) * 2, true, lm, lq, a5_0, a5_1);
    gemmT<7>(bufA, wTm, bufG, wave, lm, lq);
    gemmP<4, 7, true, true>(a4_0, a4_1, bufA, bufT, biasv + B_M2B0, 0,
                            wave, lm, lq);
    zpad(bufT, tid);
    __syncthreads();

    // ---- P5: [prefetch A6=ATW0] gcon (gemmRP, waves 0-3) + m2L1 (waves 4-7)
    sx8 a6_0[4], a6_1[4];
    loadApair<4>(ws + WS_ATW0, 112, png * 2, ph1, lm, lq, a6_0, a6_1);
    gemmRP<4, 7>(a5_0, a5_1, bufG, grc, biasv + B_ATB0, wave, lm, lq);
    gemmP<4, 4, false, true>(a5_0, a5_1, bufT, bufH2, biasv + B_M2B1, 0,
                             (wave + 4) & 7, lm, lq);
    __syncthreads();

    // ---- P6: [prefetch A7=ATW1] atL0 (100->100, relu, init=gcon)
    sx8 a7_0[4], a7_1[4];
    loadApair<4>(ws + WS_ATW1, 112, png * 2, ph1, lm, lq, a7_0, a7_1);
    gemmP<4, 7, true, false>(a6_0, a6_1, bufA, bufT, grc, 112,
                             wave, lm, lq);
    __syncthreads();

    // ---- P7: [prefetch afr8=ATW2] atL1 (100->100, relu)
    sx8 afr8[4];
    #pragma unroll
    for (int kt = 0; kt < 4; ++kt)
        afr8[kt] = *(const sx8*)(ws + WS_ATW2 + ((kt * 4 + lq) * 16 + lm) * 8);
    gemmP<4, 7, true, true>(a7_0, a7_1, bufT, bufA, biasv + B_ATB1, 0,
                            wave, lm, lq);
    __syncthreads();

    // ---- P8: scores via MFMA (ta2 @ atw2, preloaded afr8) -> scv
    {
        float atb2s = atb2[0];
        for (int mt = wave; mt < MT; mt += NW) {
            int tok = mt * 16 + lm;
            fx4 acc = {0.f, 0.f, 0.f, 0.f};
            const short* bp = bufA + tok * 8;
            #pragma unroll
            for (int kt = 0; kt < 4; ++kt) {
                sx8 b = *(const sx8*)(bp + (kt * 4 + lq) * CHH);
                acc = __builtin_amdgcn_mfma_f32_16x16x32_bf16(afr8[kt], b, acc, 0, 0, 0);
            }
            if (lq == 0) {
                float s = (acc[0] + atb2s) * maskv[tok];
                scv[tok] = (s != 0.f) ? __expf(s) : 0.f;
            }
        }
    }
    __syncthreads();

    // ---- P9: [prefetch A11=HPW0H (waves0-3), A12=HPW0] seT build
    sx8 a11_0[2], a11_1[2], a12_0[2], a12_1[2];
    if (wave < 4)
        loadApair<2>(ws + WS_HPW0H, 112, wave * 2, wave != 3, lm, lq, a11_0, a11_1);
    loadApair<2>(ws + WS_HPW0, 112, png * 2, ph1, lm, lq, a12_0, a12_1);
    for (int t = tid; t < 1536; t += TB) {
        int b = t / 96, tp = t - b * 96;
        int tau = (tp & ~7) | ((tp + ((tp >> 3) & 3) * 2) & 7);
        float v = 0.f;
        if (b < NB && tau < MTOK && tau / 20 == b) {
            float ss = 0.f;
            #pragma unroll
            for (int n = 0; n < 20; ++n) ss += scv[b * 20 + n];
            v = (ss > 0.f) ? scv[tau] / ss : 0.f;
        }
        wTm[t] = f2b(v);
    }
    __syncthreads();

    // ---- P10: wsum (gemmT: h2 x seT -> bufG chunks 0..7)
    gemmT<4>(bufH2, wTm, bufG, wave, lm, lq);
    __syncthreads();

    // ---- P11: hcon (gemmRP A11: wrc = hpb0 + wsum @ hpw0[50:100])
    gemmRP<2, 7>(a11_0, a11_1, bufG, wrc, biasv + B_HPB0, wave, lm, lq);
    __syncthreads();

    // ---- P12: [prefetch A13=HPW1] hpL0 (50->100, relu, init=hcon)
    sx8 a13_0[4], a13_1[4];
    loadApair<4>(ws + WS_HPW1, 112, png * 2, ph1, lm, lq, a13_0, a13_1);
    gemmP<2, 7, true, false>(a12_0, a12_1, bufH2, bufT, wrc, 112,
                             wave, lm, lq);
    __syncthreads();

    // ---- P13: [prefetch afr14=HPW2] hpL1 (100->100, relu)
    sx8 afr14[4];
    #pragma unroll
    for (int kt = 0; kt < 4; ++kt)
        afr14[kt] = *(const sx8*)(ws + WS_HPW2 + ((kt * 4 + lq) * 16 + lm) * 8);
    gemmP<4, 7, true, true>(a13_0, a13_1, bufT, bufA, biasv + B_HPB1, 0,
                            wave, lm, lq);
    __syncthreads();

    // ---- P14: hpL2 (100->7) -> global out (preloaded afr14)
    {
        fx4 ib = *(const fx4*)(biasv + B_HPB2 + lq * 4);
        for (int mt = wave; mt < MT; mt += NW) {
            int tok = mt * 16 + lm;
            fx4 acc = ib;
            const short* bp = bufA + tok * 8;
            #pragma unroll
            for (int kt = 0; kt < 4; ++kt) {
                sx8 b = *(const sx8*)(bp + (kt * 4 + lq) * CHH);
                acc = __builtin_amdgcn_mfma_f32_16x16x32_bf16(afr14[kt], b, acc, 0, 0, 0);
            }
            #pragma unroll
            for (int r = 0; r < 4; ++r) {
                int n = lq * 4 + r;
                if (n < 7) out[(gt0 + tok) * 7 + n] = acc[r];
            }
        }
    }
}

extern "C" void kernel_launch(void* const* d_in, const int* in_sizes, int n_in,
                              void* d_out, int out_size, void* d_ws, size_t ws_size,
                              hipStream_t stream) {
    int si = 20, wb = 0;
    if (in_sizes[0] > 1000000) { si = 0; wb = 1; }
    const float* state = (const float*)d_in[si];
    const float* W[20];
    for (int i = 0; i < 20; ++i) W[i] = (const float*)d_in[wb + i];
    float* out = (float*)d_out;
    short* ws = (short*)d_ws;
    int Btot = in_sizes[si] / (20 * 14);
    int nblocks = Btot / NB;   // 4 b's (80 tokens) per block -> 8192

    hipLaunchKernelGGL(stage_weights, dim3(128), dim3(256), 0, stream,
        W[0], W[2], W[4], W[6], W[8], W[10], W[14], W[16], W[18], W[12], ws);

    hipLaunchKernelGGL(sp_mfma_bf16, dim3(nblocks), dim3(TB), 0, stream,
        state,
        W[1], W[3],           // m1b0, m1b1
        W[5], W[7],           // m2b0, m2b1
        W[9], W[11],          // atb0, atb1
        W[13],                // atb2
        W[15], W[17], W[19],  // hpb0, hpb1, hpb2
        ws, out);
}